// Round 1
// baseline (1153.711 us; speedup 1.0000x reference)
//
#include <hip/hip_runtime.h>

// Problem constants (from reference)
#define C_IMG 16
#define GRIDSZ 128
#define SLOPE 0.3f
#define SCALE 0.1f

// ---------------------------------------------------------------------------
// Degree count (int atomics)
__global__ __launch_bounds__(256) void k_deg(const int* __restrict__ edst,
                                             int* __restrict__ deg, int ne) {
    int e = blockIdx.x * 256 + threadIdx.x;
    if (e >= ne) return;
    atomicAdd(&deg[edst[e]], 1);
}

// Single-block exclusive prefix scan: deg[0..nv) -> rowStart[0..nv]
__global__ __launch_bounds__(1024) void k_scan(const int* __restrict__ deg,
                                               int* __restrict__ rowStart, int nv) {
    __shared__ int buf[1024];
    __shared__ int carry;
    int tid = threadIdx.x;
    if (tid == 0) carry = 0;
    __syncthreads();
    for (int base = 0; base < nv; base += 1024) {
        int v = base + tid;
        int d = (v < nv) ? deg[v] : 0;
        buf[tid] = d;
        __syncthreads();
        for (int off = 1; off < 1024; off <<= 1) {
            int t2 = (tid >= off) ? buf[tid - off] : 0;
            __syncthreads();
            buf[tid] += t2;
            __syncthreads();
        }
        int c0 = carry;
        if (v < nv) rowStart[v] = c0 + buf[tid] - d;
        int csum = buf[1023];
        __syncthreads();
        if (tid == 0) carry = c0 + csum;
        __syncthreads();
    }
    if (tid == 0) rowStart[nv] = carry;
}

// inv_deg + cursor init
__global__ __launch_bounds__(256) void k_vinit(const int* __restrict__ deg,
                                               const int* __restrict__ rowStart,
                                               float* __restrict__ invdeg,
                                               int* __restrict__ cursor, int nv) {
    int v = blockIdx.x * 256 + threadIdx.x;
    if (v >= nv) return;
    int d = deg[v];
    invdeg[v] = 1.0f / (float)(d > 1 ? d : 1);
    cursor[v] = rowStart[v];
}

// CSR fill: csrSrc[pos] = src, grouped by dst
__global__ __launch_bounds__(256) void k_fill(const int* __restrict__ esrc,
                                              const int* __restrict__ edst,
                                              int* __restrict__ cursor,
                                              int* __restrict__ csrSrc, int ne) {
    int e = blockIdx.x * 256 + threadIdx.x;
    if (e >= ne) return;
    int pos = atomicAdd(&cursor[edst[e]], 1);
    csrSrc[pos] = esrc[e];
}

// ---------------------------------------------------------------------------
// Trilinear sample: one thread per (vertex, channel). feats stride 20:
// cols 0..2 = verts/128, cols 3..18 = sampled channels, col 19 = 0 (pad).
__global__ __launch_bounds__(256) void k_sample(const float* __restrict__ img,
                                                const float* __restrict__ verts,
                                                float* __restrict__ feats, int nv) {
    int t = blockIdx.x * 256 + threadIdx.x;
    int v = t >> 4;
    int c = t & 15;
    if (v >= nv) return;
    float px = verts[v * 3 + 0];
    float py = verts[v * 3 + 1];
    float pz = verts[v * 3 + 2];
    float cx = fminf(fmaxf(px, 0.0f), 127.0f);
    float cy = fminf(fmaxf(py, 0.0f), 127.0f);
    float cz = fminf(fmaxf(pz, 0.0f), 127.0f);
    float fx = floorf(cx), fy = floorf(cy), fz = floorf(cz);
    int x0 = (int)fx, y0 = (int)fy, z0 = (int)fz;
    int x1 = min(x0 + 1, 127), y1 = min(y0 + 1, 127), z1 = min(z0 + 1, 127);
    float wx = cx - fx, wy = cy - fy, wz = cz - fz;
    const float* ic = img + (size_t)c * (GRIDSZ * GRIDSZ * GRIDSZ);
    #define G(X, Y, Z) ic[((X) * GRIDSZ + (Y)) * GRIDSZ + (Z)]
    float c000 = G(x0, y0, z0), c001 = G(x0, y0, z1);
    float c010 = G(x0, y1, z0), c011 = G(x0, y1, z1);
    float c100 = G(x1, y0, z0), c101 = G(x1, y0, z1);
    float c110 = G(x1, y1, z0), c111 = G(x1, y1, z1);
    #undef G
    float c00 = c000 * (1.0f - wz) + c001 * wz;
    float c01 = c010 * (1.0f - wz) + c011 * wz;
    float c10 = c100 * (1.0f - wz) + c101 * wz;
    float c11 = c110 * (1.0f - wz) + c111 * wz;
    float r = (c00 * (1.0f - wy) + c01 * wy) * (1.0f - wx) +
              (c10 * (1.0f - wy) + c11 * wy) * wx;
    size_t row = (size_t)v * 20;
    feats[row + 3 + c] = r;
    if (c < 3) feats[row + c] = verts[v * 3 + c] * (1.0f / 128.0f);
    if (c == 0) feats[row + 19] = 0.0f;
}

// ---------------------------------------------------------------------------
// CSR gather-sum: nb[v] = sum over in-edges of x[src]. One thread per
// (vertex, float4 chunk); stride S floats, S % 4 == 0, pads are zeroed in x.
template <int S>
__global__ __launch_bounds__(256) void k_gather(const float* __restrict__ x,
                                                const int* __restrict__ rowStart,
                                                const int* __restrict__ csrSrc,
                                                float* __restrict__ nb, int nv) {
    constexpr int NCH = S / 4;
    int t = blockIdx.x * 256 + threadIdx.x;
    int v = t / NCH;
    if (v >= nv) return;
    int ch = t - v * NCH;
    int beg = rowStart[v];
    int end = rowStart[v + 1];
    float4 acc = make_float4(0.f, 0.f, 0.f, 0.f);
    for (int j = beg; j < end; ++j) {
        int s = csrSrc[j];
        float4 q = ((const float4*)(x + (size_t)s * S))[ch];
        acc.x += q.x; acc.y += q.y; acc.z += q.z; acc.w += q.w;
    }
    ((float4*)(nb + (size_t)v * S))[ch] = acc;
}

// ---------------------------------------------------------------------------
// Edge-conv dense part: out[v][co] = act(x[v]@Ws + inv_deg[v]*(nb[v]@Wn) + b)
// One thread per (v, co). Output stride == COUT.
template <int CIN, int COUT, int SX, bool RELU>
__global__ __launch_bounds__(256) void k_layer(const float* __restrict__ x,
                                               const float* __restrict__ nb,
                                               const float* __restrict__ invdeg,
                                               const float* __restrict__ Ws,
                                               const float* __restrict__ Wn,
                                               const float* __restrict__ b,
                                               float* __restrict__ out, int nv) {
    int t = blockIdx.x * 256 + threadIdx.x;
    int v = t / COUT;
    if (v >= nv) return;
    int co = t - v * COUT;
    const float* xr = x + (size_t)v * SX;
    const float* nr = nb + (size_t)v * SX;
    float acc = b[co];
    float accn = 0.0f;
    #pragma unroll 8
    for (int k = 0; k < CIN; ++k) {
        acc += xr[k] * Ws[k * COUT + co];
        accn += nr[k] * Wn[k * COUT + co];
    }
    acc += accn * invdeg[v];
    if (RELU) acc = (acc >= 0.0f) ? acc : SLOPE * acc;
    out[(size_t)v * COUT + co] = acc;
}

// Pre-multiply for layer 3: z[v][j] = h3[v] @ Wn3 (j<3), z stride 4, pad 0.
__global__ __launch_bounds__(256) void k_premul(const float* __restrict__ h,
                                                const float* __restrict__ wn,
                                                float* __restrict__ z, int nv) {
    int t = blockIdx.x * 256 + threadIdx.x;
    int v = t >> 2;
    int j = t & 3;
    if (v >= nv) return;
    if (j == 3) { z[(size_t)v * 4 + 3] = 0.0f; return; }
    const float* hr = h + (size_t)v * 64;
    float acc = 0.0f;
    #pragma unroll 8
    for (int k = 0; k < 64; ++k) acc += hr[k] * wn[k * 3 + j];
    z[(size_t)v * 4 + j] = acc;
}

// Final: out[v][j] = verts[v][j] + SCALE*(h3[v]@Ws3[:,j] + nb3[v][j]*inv_deg + b3[j])
__global__ __launch_bounds__(256) void k_final(const float* __restrict__ h,
                                               const float* __restrict__ nb,
                                               const float* __restrict__ invdeg,
                                               const float* __restrict__ ws,
                                               const float* __restrict__ b,
                                               const float* __restrict__ verts,
                                               float* __restrict__ out, int nv) {
    int t = blockIdx.x * 256 + threadIdx.x;
    int v = t / 3;
    if (v >= nv) return;
    int j = t - v * 3;
    const float* hr = h + (size_t)v * 64;
    float acc = b[j];
    #pragma unroll 8
    for (int k = 0; k < 64; ++k) acc += hr[k] * ws[k * 3 + j];
    acc += nb[(size_t)v * 4 + j] * invdeg[v];
    out[(size_t)v * 3 + j] = verts[(size_t)v * 3 + j] + SCALE * acc;
}

// ---------------------------------------------------------------------------
extern "C" void kernel_launch(void* const* d_in, const int* in_sizes, int n_in,
                              void* d_out, int out_size, void* d_ws, size_t ws_size,
                              hipStream_t stream) {
    const float* img   = (const float*)d_in[0];
    const float* verts = (const float*)d_in[1];
    const int*   esrc  = (const int*)d_in[2];
    const int*   edst  = (const int*)d_in[3];
    const float* ws0 = (const float*)d_in[4];
    const float* wn0 = (const float*)d_in[5];
    const float* b0  = (const float*)d_in[6];
    const float* ws1 = (const float*)d_in[7];
    const float* wn1 = (const float*)d_in[8];
    const float* b1  = (const float*)d_in[9];
    const float* ws2 = (const float*)d_in[10];
    const float* wn2 = (const float*)d_in[11];
    const float* b2  = (const float*)d_in[12];
    const float* ws3 = (const float*)d_in[13];
    const float* wn3 = (const float*)d_in[14];
    const float* b3  = (const float*)d_in[15];

    const int nv = in_sizes[1] / 3;
    const int ne = in_sizes[2];

    char* base = (char*)d_ws;
    size_t off = 0;
    auto alloc = [&](size_t bytes) -> void* {
        off = (off + 255) & ~(size_t)255;
        void* p = base + off;
        off += bytes;
        return p;
    };
    int*   deg      = (int*)alloc((size_t)nv * 4);
    float* invdeg   = (float*)alloc((size_t)nv * 4);
    int*   rowStart = (int*)alloc((size_t)(nv + 1) * 4);
    int*   cursor   = (int*)alloc((size_t)nv * 4);
    int*   csrSrc   = (int*)alloc((size_t)ne * 4);
    float* A        = (float*)alloc((size_t)nv * 64 * 4);  // feats(20) then h2(64)
    float* B        = (float*)alloc((size_t)nv * 64 * 4);  // h1(32) then h3(64)
    float* NB       = (float*)alloc((size_t)nv * 64 * 4);  // neighbor sums
    float* Z        = (float*)alloc((size_t)nv * 4 * 4);   // premultiplied layer-3

    auto blocks = [](long long n) { return (int)((n + 255) / 256); };

    // CSR build
    hipMemsetAsync(deg, 0, (size_t)nv * 4, stream);
    k_deg<<<blocks(ne), 256, 0, stream>>>(edst, deg, ne);
    k_scan<<<1, 1024, 0, stream>>>(deg, rowStart, nv);
    k_vinit<<<blocks(nv), 256, 0, stream>>>(deg, rowStart, invdeg, cursor, nv);
    k_fill<<<blocks(ne), 256, 0, stream>>>(esrc, edst, cursor, csrSrc, ne);

    // Features
    k_sample<<<blocks((long long)nv * 16), 256, 0, stream>>>(img, verts, A, nv);

    // Layer 0: 19 -> 32
    k_gather<20><<<blocks((long long)nv * 5), 256, 0, stream>>>(A, rowStart, csrSrc, NB, nv);
    k_layer<19, 32, 20, true><<<blocks((long long)nv * 32), 256, 0, stream>>>(
        A, NB, invdeg, ws0, wn0, b0, B, nv);

    // Layer 1: 32 -> 64
    k_gather<32><<<blocks((long long)nv * 8), 256, 0, stream>>>(B, rowStart, csrSrc, NB, nv);
    k_layer<32, 64, 32, true><<<blocks((long long)nv * 64), 256, 0, stream>>>(
        B, NB, invdeg, ws1, wn1, b1, A, nv);

    // Layer 2: 64 -> 64
    k_gather<64><<<blocks((long long)nv * 16), 256, 0, stream>>>(A, rowStart, csrSrc, NB, nv);
    k_layer<64, 64, 64, true><<<blocks((long long)nv * 64), 256, 0, stream>>>(
        A, NB, invdeg, ws2, wn2, b2, B, nv);

    // Layer 3: pre-multiply by Wn3 (64->3), gather 4 floats, fuse final update
    k_premul<<<blocks((long long)nv * 4), 256, 0, stream>>>(B, wn3, Z, nv);
    k_gather<4><<<blocks((long long)nv * 1), 256, 0, stream>>>(Z, rowStart, csrSrc, NB, nv);
    k_final<<<blocks((long long)nv * 3), 256, 0, stream>>>(
        B, NB, invdeg, ws3, b3, verts, (float*)d_out, nv);
}

// Round 2
// 942.757 us; speedup vs baseline: 1.2238x; 1.2238x over previous
//
#include <hip/hip_runtime.h>

// Problem constants (from reference)
#define C_IMG 16
#define GRIDSZ 128
#define SLOPE 0.3f
#define SCALE 0.1f

// ---------------------------------------------------------------------------
// Degree count (int atomics)
__global__ __launch_bounds__(256) void k_deg(const int* __restrict__ edst,
                                             int* __restrict__ deg, int ne) {
    int e = blockIdx.x * 256 + threadIdx.x;
    if (e >= ne) return;
    atomicAdd(&deg[edst[e]], 1);
}

// Single-block exclusive prefix scan: deg[0..nv) -> rowStart[0..nv]
__global__ __launch_bounds__(1024) void k_scan(const int* __restrict__ deg,
                                               int* __restrict__ rowStart, int nv) {
    __shared__ int buf[1024];
    __shared__ int carry;
    int tid = threadIdx.x;
    if (tid == 0) carry = 0;
    __syncthreads();
    for (int base = 0; base < nv; base += 1024) {
        int v = base + tid;
        int d = (v < nv) ? deg[v] : 0;
        buf[tid] = d;
        __syncthreads();
        for (int off = 1; off < 1024; off <<= 1) {
            int t2 = (tid >= off) ? buf[tid - off] : 0;
            __syncthreads();
            buf[tid] += t2;
            __syncthreads();
        }
        int c0 = carry;
        if (v < nv) rowStart[v] = c0 + buf[tid] - d;
        int csum = buf[1023];
        __syncthreads();
        if (tid == 0) carry = c0 + csum;
        __syncthreads();
    }
    if (tid == 0) rowStart[nv] = carry;
}

// inv_deg + cursor init
__global__ __launch_bounds__(256) void k_vinit(const int* __restrict__ deg,
                                               const int* __restrict__ rowStart,
                                               float* __restrict__ invdeg,
                                               int* __restrict__ cursor, int nv) {
    int v = blockIdx.x * 256 + threadIdx.x;
    if (v >= nv) return;
    int d = deg[v];
    invdeg[v] = 1.0f / (float)(d > 1 ? d : 1);
    cursor[v] = rowStart[v];
}

// CSR fill: csrSrc[pos] = src, grouped by dst
__global__ __launch_bounds__(256) void k_fill(const int* __restrict__ esrc,
                                              const int* __restrict__ edst,
                                              int* __restrict__ cursor,
                                              int* __restrict__ csrSrc, int ne) {
    int e = blockIdx.x * 256 + threadIdx.x;
    if (e >= ne) return;
    int pos = atomicAdd(&cursor[edst[e]], 1);
    csrSrc[pos] = esrc[e];
}

// ---------------------------------------------------------------------------
// Trilinear sample: one thread per (vertex, channel). feats stride 20:
// cols 0..2 = verts/128, cols 3..18 = sampled channels, col 19 = 0 (pad).
__global__ __launch_bounds__(256) void k_sample(const float* __restrict__ img,
                                                const float* __restrict__ verts,
                                                float* __restrict__ feats, int nv) {
    int t = blockIdx.x * 256 + threadIdx.x;
    int v = t >> 4;
    int c = t & 15;
    if (v >= nv) return;
    float px = verts[v * 3 + 0];
    float py = verts[v * 3 + 1];
    float pz = verts[v * 3 + 2];
    float cx = fminf(fmaxf(px, 0.0f), 127.0f);
    float cy = fminf(fmaxf(py, 0.0f), 127.0f);
    float cz = fminf(fmaxf(pz, 0.0f), 127.0f);
    float fx = floorf(cx), fy = floorf(cy), fz = floorf(cz);
    int x0 = (int)fx, y0 = (int)fy, z0 = (int)fz;
    int x1 = min(x0 + 1, 127), y1 = min(y0 + 1, 127), z1 = min(z0 + 1, 127);
    float wx = cx - fx, wy = cy - fy, wz = cz - fz;
    const float* ic = img + (size_t)c * (GRIDSZ * GRIDSZ * GRIDSZ);
    #define G(X, Y, Z) ic[((X) * GRIDSZ + (Y)) * GRIDSZ + (Z)]
    float c000 = G(x0, y0, z0), c001 = G(x0, y0, z1);
    float c010 = G(x0, y1, z0), c011 = G(x0, y1, z1);
    float c100 = G(x1, y0, z0), c101 = G(x1, y0, z1);
    float c110 = G(x1, y1, z0), c111 = G(x1, y1, z1);
    #undef G
    float c00 = c000 * (1.0f - wz) + c001 * wz;
    float c01 = c010 * (1.0f - wz) + c011 * wz;
    float c10 = c100 * (1.0f - wz) + c101 * wz;
    float c11 = c110 * (1.0f - wz) + c111 * wz;
    float r = (c00 * (1.0f - wy) + c01 * wy) * (1.0f - wx) +
              (c10 * (1.0f - wy) + c11 * wy) * wx;
    size_t row = (size_t)v * 20;
    feats[row + 3 + c] = r;
    if (c < 3) feats[row + c] = verts[v * 3 + c] * (1.0f / 128.0f);
    if (c == 0) feats[row + 19] = 0.0f;
}

// ---------------------------------------------------------------------------
// CSR gather-sum: nb[v] = sum over in-edges of x[src]. One thread per
// (vertex, float4 chunk); stride S floats, S % 4 == 0, pads are zeroed in x.
template <int S>
__global__ __launch_bounds__(256) void k_gather(const float* __restrict__ x,
                                                const int* __restrict__ rowStart,
                                                const int* __restrict__ csrSrc,
                                                float* __restrict__ nb, int nv) {
    constexpr int NCH = S / 4;
    int t = blockIdx.x * 256 + threadIdx.x;
    int v = t / NCH;
    if (v >= nv) return;
    int ch = t - v * NCH;
    int beg = rowStart[v];
    int end = rowStart[v + 1];
    float4 acc = make_float4(0.f, 0.f, 0.f, 0.f);
    for (int j = beg; j < end; ++j) {
        int s = csrSrc[j];
        float4 q = ((const float4*)(x + (size_t)s * S))[ch];
        acc.x += q.x; acc.y += q.y; acc.z += q.z; acc.w += q.w;
    }
    ((float4*)(nb + (size_t)v * S))[ch] = acc;
}

// ---------------------------------------------------------------------------
// Edge-conv dense part, load-amortized:
//   out[v][co] = act(x[v]@Ws + inv_deg[v]*(nb[v]@Wn) + b)
// Ws/Wn staged in LDS (zero-padded K). Each thread: VPT vertices x 8 outputs.
// Per k4 iteration: 8 global float4 + 16 ds_read_b128 + 256 FMA -> FMA-bound.
template <int CIN, int COUT, int SX, bool RELU>
__global__ __launch_bounds__(256) void k_layer(const float* __restrict__ x,
                                               const float* __restrict__ nb,
                                               const float* __restrict__ invdeg,
                                               const float* __restrict__ Ws,
                                               const float* __restrict__ Wn,
                                               const float* __restrict__ b,
                                               float* __restrict__ out, int nv) {
    constexpr int GR = COUT / 8;              // co-groups of 8 per vertex
    constexpr int VPT = 4;                    // vertices per thread
    constexpr int TPB = 256;
    constexpr int VPB = (TPB / GR) * VPT;     // vertices per block
    constexpr int KP = (CIN + 3) & ~3;        // K padded to multiple of 4
    __shared__ float ws_s[KP * COUT];
    __shared__ float wn_s[KP * COUT];
    for (int i = threadIdx.x; i < KP * COUT; i += TPB) {
        int k = i / COUT, c = i - k * COUT;
        float vs = 0.f, vn = 0.f;
        if (k < CIN) { vs = Ws[k * COUT + c]; vn = Wn[k * COUT + c]; }
        ws_s[i] = vs;
        wn_s[i] = vn;
    }
    __syncthreads();

    const int g = threadIdx.x % GR;
    const int co = g * 8;
    const int vt = threadIdx.x / GR;
    const int v0 = blockIdx.x * VPB + vt * VPT;

    float acc_s[VPT][8], acc_n[VPT][8];
    #pragma unroll
    for (int u = 0; u < VPT; ++u)
        #pragma unroll
        for (int i = 0; i < 8; ++i) { acc_s[u][i] = 0.f; acc_n[u][i] = 0.f; }

    for (int k = 0; k < KP; k += 4) {
        float4 xq[VPT], nq[VPT];
        #pragma unroll
        for (int u = 0; u < VPT; ++u) {
            int v = v0 + u;
            if (v < nv) {
                xq[u] = *(const float4*)(x + (size_t)v * SX + k);
                nq[u] = *(const float4*)(nb + (size_t)v * SX + k);
            } else {
                xq[u] = make_float4(0.f, 0.f, 0.f, 0.f);
                nq[u] = make_float4(0.f, 0.f, 0.f, 0.f);
            }
        }
        #pragma unroll
        for (int j = 0; j < 4; ++j) {
            const float4 wsa = *(const float4*)(ws_s + (k + j) * COUT + co);
            const float4 wsb = *(const float4*)(ws_s + (k + j) * COUT + co + 4);
            const float4 wna = *(const float4*)(wn_s + (k + j) * COUT + co);
            const float4 wnb = *(const float4*)(wn_s + (k + j) * COUT + co + 4);
            #pragma unroll
            for (int u = 0; u < VPT; ++u) {
                float xv = (j == 0) ? xq[u].x : (j == 1) ? xq[u].y : (j == 2) ? xq[u].z : xq[u].w;
                float nw = (j == 0) ? nq[u].x : (j == 1) ? nq[u].y : (j == 2) ? nq[u].z : nq[u].w;
                acc_s[u][0] += xv * wsa.x; acc_s[u][1] += xv * wsa.y;
                acc_s[u][2] += xv * wsa.z; acc_s[u][3] += xv * wsa.w;
                acc_s[u][4] += xv * wsb.x; acc_s[u][5] += xv * wsb.y;
                acc_s[u][6] += xv * wsb.z; acc_s[u][7] += xv * wsb.w;
                acc_n[u][0] += nw * wna.x; acc_n[u][1] += nw * wna.y;
                acc_n[u][2] += nw * wna.z; acc_n[u][3] += nw * wna.w;
                acc_n[u][4] += nw * wnb.x; acc_n[u][5] += nw * wnb.y;
                acc_n[u][6] += nw * wnb.z; acc_n[u][7] += nw * wnb.w;
            }
        }
    }

    #pragma unroll
    for (int u = 0; u < VPT; ++u) {
        int v = v0 + u;
        if (v >= nv) continue;
        float id = invdeg[v];
        float r[8];
        #pragma unroll
        for (int i = 0; i < 8; ++i) {
            float t = acc_s[u][i] + acc_n[u][i] * id + b[co + i];
            r[i] = (!RELU || t >= 0.f) ? t : SLOPE * t;
        }
        float4* op = (float4*)(out + (size_t)v * COUT + co);
        op[0] = make_float4(r[0], r[1], r[2], r[3]);
        op[1] = make_float4(r[4], r[5], r[6], r[7]);
    }
}

// Pre-multiply for layer 3: z[v][j] = h3[v] @ Wn3 (j<3), z stride 4, pad 0.
// One thread per vertex; h via float4; Wn3 staged in LDS.
__global__ __launch_bounds__(256) void k_premul(const float* __restrict__ h,
                                                const float* __restrict__ wn,
                                                float* __restrict__ z, int nv) {
    __shared__ float w_s[64 * 3];
    if (threadIdx.x < 64 * 3) w_s[threadIdx.x] = wn[threadIdx.x];
    __syncthreads();
    int v = blockIdx.x * 256 + threadIdx.x;
    if (v >= nv) return;
    const float4* hr = (const float4*)(h + (size_t)v * 64);
    float a0 = 0.f, a1 = 0.f, a2 = 0.f;
    #pragma unroll
    for (int q = 0; q < 16; ++q) {
        float4 hv = hr[q];
        int k = q * 4;
        a0 += hv.x * w_s[k * 3 + 0] + hv.y * w_s[k * 3 + 3] + hv.z * w_s[k * 3 + 6] + hv.w * w_s[k * 3 + 9];
        a1 += hv.x * w_s[k * 3 + 1] + hv.y * w_s[k * 3 + 4] + hv.z * w_s[k * 3 + 7] + hv.w * w_s[k * 3 + 10];
        a2 += hv.x * w_s[k * 3 + 2] + hv.y * w_s[k * 3 + 5] + hv.z * w_s[k * 3 + 8] + hv.w * w_s[k * 3 + 11];
    }
    *((float4*)(z + (size_t)v * 4)) = make_float4(a0, a1, a2, 0.f);
}

// Final: out[v][j] = verts[v][j] + SCALE*(h3[v]@Ws3[:,j] + nb3[v][j]*inv_deg + b3[j])
__global__ __launch_bounds__(256) void k_final(const float* __restrict__ h,
                                               const float* __restrict__ nb,
                                               const float* __restrict__ invdeg,
                                               const float* __restrict__ ws,
                                               const float* __restrict__ b,
                                               const float* __restrict__ verts,
                                               float* __restrict__ out, int nv) {
    __shared__ float w_s[64 * 3];
    if (threadIdx.x < 64 * 3) w_s[threadIdx.x] = ws[threadIdx.x];
    __syncthreads();
    int v = blockIdx.x * 256 + threadIdx.x;
    if (v >= nv) return;
    const float4* hr = (const float4*)(h + (size_t)v * 64);
    float a0 = b[0], a1 = b[1], a2 = b[2];
    #pragma unroll
    for (int q = 0; q < 16; ++q) {
        float4 hv = hr[q];
        int k = q * 4;
        a0 += hv.x * w_s[k * 3 + 0] + hv.y * w_s[k * 3 + 3] + hv.z * w_s[k * 3 + 6] + hv.w * w_s[k * 3 + 9];
        a1 += hv.x * w_s[k * 3 + 1] + hv.y * w_s[k * 3 + 4] + hv.z * w_s[k * 3 + 7] + hv.w * w_s[k * 3 + 10];
        a2 += hv.x * w_s[k * 3 + 2] + hv.y * w_s[k * 3 + 5] + hv.z * w_s[k * 3 + 8] + hv.w * w_s[k * 3 + 11];
    }
    float id = invdeg[v];
    float4 nq = *((const float4*)(nb + (size_t)v * 4));
    a0 += nq.x * id; a1 += nq.y * id; a2 += nq.z * id;
    out[(size_t)v * 3 + 0] = verts[(size_t)v * 3 + 0] + SCALE * a0;
    out[(size_t)v * 3 + 1] = verts[(size_t)v * 3 + 1] + SCALE * a1;
    out[(size_t)v * 3 + 2] = verts[(size_t)v * 3 + 2] + SCALE * a2;
}

// ---------------------------------------------------------------------------
extern "C" void kernel_launch(void* const* d_in, const int* in_sizes, int n_in,
                              void* d_out, int out_size, void* d_ws, size_t ws_size,
                              hipStream_t stream) {
    const float* img   = (const float*)d_in[0];
    const float* verts = (const float*)d_in[1];
    const int*   esrc  = (const int*)d_in[2];
    const int*   edst  = (const int*)d_in[3];
    const float* ws0 = (const float*)d_in[4];
    const float* wn0 = (const float*)d_in[5];
    const float* b0  = (const float*)d_in[6];
    const float* ws1 = (const float*)d_in[7];
    const float* wn1 = (const float*)d_in[8];
    const float* b1  = (const float*)d_in[9];
    const float* ws2 = (const float*)d_in[10];
    const float* wn2 = (const float*)d_in[11];
    const float* b2  = (const float*)d_in[12];
    const float* ws3 = (const float*)d_in[13];
    const float* wn3 = (const float*)d_in[14];
    const float* b3  = (const float*)d_in[15];

    const int nv = in_sizes[1] / 3;
    const int ne = in_sizes[2];

    char* base = (char*)d_ws;
    size_t off = 0;
    auto alloc = [&](size_t bytes) -> void* {
        off = (off + 255) & ~(size_t)255;
        void* p = base + off;
        off += bytes;
        return p;
    };
    int*   deg      = (int*)alloc((size_t)nv * 4);
    float* invdeg   = (float*)alloc((size_t)nv * 4);
    int*   rowStart = (int*)alloc((size_t)(nv + 1) * 4);
    int*   cursor   = (int*)alloc((size_t)nv * 4);
    int*   csrSrc   = (int*)alloc((size_t)ne * 4);
    float* A        = (float*)alloc((size_t)nv * 64 * 4);  // feats(20) then h2(64)
    float* B        = (float*)alloc((size_t)nv * 64 * 4);  // h1(32) then h3(64)
    float* NB       = (float*)alloc((size_t)nv * 64 * 4);  // neighbor sums
    float* Z        = (float*)alloc((size_t)nv * 4 * 4);   // premultiplied layer-3

    auto blocks = [](long long n) { return (int)((n + 255) / 256); };

    // CSR build
    hipMemsetAsync(deg, 0, (size_t)nv * 4, stream);
    k_deg<<<blocks(ne), 256, 0, stream>>>(edst, deg, ne);
    k_scan<<<1, 1024, 0, stream>>>(deg, rowStart, nv);
    k_vinit<<<blocks(nv), 256, 0, stream>>>(deg, rowStart, invdeg, cursor, nv);
    k_fill<<<blocks(ne), 256, 0, stream>>>(esrc, edst, cursor, csrSrc, ne);

    // Features
    k_sample<<<blocks((long long)nv * 16), 256, 0, stream>>>(img, verts, A, nv);

    // Layer 0: 19 -> 32  (VPB = (256/4)*4 = 256)
    k_gather<20><<<blocks((long long)nv * 5), 256, 0, stream>>>(A, rowStart, csrSrc, NB, nv);
    k_layer<19, 32, 20, true><<<(nv + 255) / 256, 256, 0, stream>>>(
        A, NB, invdeg, ws0, wn0, b0, B, nv);

    // Layer 1: 32 -> 64  (VPB = (256/8)*4 = 128)
    k_gather<32><<<blocks((long long)nv * 8), 256, 0, stream>>>(B, rowStart, csrSrc, NB, nv);
    k_layer<32, 64, 32, true><<<(nv + 127) / 128, 256, 0, stream>>>(
        B, NB, invdeg, ws1, wn1, b1, A, nv);

    // Layer 2: 64 -> 64  (VPB = 128)
    k_gather<64><<<blocks((long long)nv * 16), 256, 0, stream>>>(A, rowStart, csrSrc, NB, nv);
    k_layer<64, 64, 64, true><<<(nv + 127) / 128, 256, 0, stream>>>(
        A, NB, invdeg, ws2, wn2, b2, B, nv);

    // Layer 3: pre-multiply by Wn3 (64->3), gather 4 floats, fuse final update
    k_premul<<<blocks(nv), 256, 0, stream>>>(B, wn3, Z, nv);
    k_gather<4><<<blocks(nv), 256, 0, stream>>>(Z, rowStart, csrSrc, NB, nv);
    k_final<<<blocks(nv), 256, 0, stream>>>(
        B, NB, invdeg, ws3, b3, verts, (float*)d_out, nv);
}

// Round 3
// 779.624 us; speedup vs baseline: 1.4798x; 1.2092x over previous
//
#include <hip/hip_runtime.h>

// Problem constants (from reference)
#define C_IMG 16
#define GRIDSZ 128
#define SLOPE 0.3f
#define SCALE 0.1f
#define SCAN_TILE 1024   // elements per scan-pass-1 block (256 thr x 4)

// ---------------------------------------------------------------------------
// Degree count (int atomics)
__global__ __launch_bounds__(256) void k_deg(const int* __restrict__ edst,
                                             int* __restrict__ deg, int ne) {
    int e = blockIdx.x * 256 + threadIdx.x;
    if (e >= ne) return;
    atomicAdd(&deg[edst[e]], 1);
}

// Multi-block scan pass 1: each block scans a SCAN_TILE tile of deg into
// tile-local exclusive prefix (written to rowStart) + tile total (partials).
__global__ __launch_bounds__(256) void k_scan1(const int* __restrict__ deg,
                                               int* __restrict__ rowStart,
                                               int* __restrict__ partials, int nv) {
    __shared__ int ssum[256];
    const int tid = threadIdx.x;
    const int idx = blockIdx.x * SCAN_TILE + tid * 4;
    int d0 = 0, d1 = 0, d2 = 0, d3 = 0;
    if (idx + 3 < nv) {
        int4 q = *(const int4*)(deg + idx);
        d0 = q.x; d1 = q.y; d2 = q.z; d3 = q.w;
    } else {
        if (idx + 0 < nv) d0 = deg[idx + 0];
        if (idx + 1 < nv) d1 = deg[idx + 1];
        if (idx + 2 < nv) d2 = deg[idx + 2];
        if (idx + 3 < nv) d3 = deg[idx + 3];
    }
    const int tsum = d0 + d1 + d2 + d3;
    ssum[tid] = tsum;
    __syncthreads();
    #pragma unroll
    for (int off = 1; off < 256; off <<= 1) {
        int t = (tid >= off) ? ssum[tid - off] : 0;
        __syncthreads();
        ssum[tid] += t;
        __syncthreads();
    }
    const int excl = ssum[tid] - tsum;
    if (tid == 255) partials[blockIdx.x] = ssum[255];
    if (idx + 0 < nv) rowStart[idx + 0] = excl;
    if (idx + 1 < nv) rowStart[idx + 1] = excl + d0;
    if (idx + 2 < nv) rowStart[idx + 2] = excl + d0 + d1;
    if (idx + 3 < nv) rowStart[idx + 3] = excl + d0 + d1 + d2;
}

// Pass 2: exclusive scan of tile totals in place (np <= 256).
__global__ __launch_bounds__(256) void k_scan2(int* __restrict__ partials, int np) {
    __shared__ int buf[256];
    const int tid = threadIdx.x;
    const int v = (tid < np) ? partials[tid] : 0;
    buf[tid] = v;
    __syncthreads();
    #pragma unroll
    for (int off = 1; off < 256; off <<= 1) {
        int t = (tid >= off) ? buf[tid - off] : 0;
        __syncthreads();
        buf[tid] += t;
        __syncthreads();
    }
    if (tid < np) partials[tid] = buf[tid] - v;
}

// Pass 3 + vertex init: rowStart += tile offset; cursor/invdeg; rowStart[nv]=ne.
__global__ __launch_bounds__(256) void k_vinit(const int* __restrict__ deg,
                                               int* __restrict__ rowStart,
                                               const int* __restrict__ partials,
                                               float* __restrict__ invdeg,
                                               int* __restrict__ cursor,
                                               int nv, int ne) {
    int v = blockIdx.x * 256 + threadIdx.x;
    if (v > nv) return;
    if (v == nv) { rowStart[nv] = ne; return; }
    int rs = rowStart[v] + partials[v / SCAN_TILE];
    rowStart[v] = rs;
    cursor[v] = rs;
    int d = deg[v];
    invdeg[v] = 1.0f / (float)(d > 1 ? d : 1);
}

// CSR fill: csrSrc[pos] = src, grouped by dst
__global__ __launch_bounds__(256) void k_fill(const int* __restrict__ esrc,
                                              const int* __restrict__ edst,
                                              int* __restrict__ cursor,
                                              int* __restrict__ csrSrc, int ne) {
    int e = blockIdx.x * 256 + threadIdx.x;
    if (e >= ne) return;
    int pos = atomicAdd(&cursor[edst[e]], 1);
    csrSrc[pos] = esrc[e];
}

// ---------------------------------------------------------------------------
// Trilinear sample: one thread per (vertex, channel). feats stride 20:
// cols 0..2 = verts/128, cols 3..18 = sampled channels, col 19 = 0 (pad).
__global__ __launch_bounds__(256) void k_sample(const float* __restrict__ img,
                                                const float* __restrict__ verts,
                                                float* __restrict__ feats, int nv) {
    int t = blockIdx.x * 256 + threadIdx.x;
    int v = t >> 4;
    int c = t & 15;
    if (v >= nv) return;
    float px = verts[v * 3 + 0];
    float py = verts[v * 3 + 1];
    float pz = verts[v * 3 + 2];
    float cx = fminf(fmaxf(px, 0.0f), 127.0f);
    float cy = fminf(fmaxf(py, 0.0f), 127.0f);
    float cz = fminf(fmaxf(pz, 0.0f), 127.0f);
    float fx = floorf(cx), fy = floorf(cy), fz = floorf(cz);
    int x0 = (int)fx, y0 = (int)fy, z0 = (int)fz;
    int x1 = min(x0 + 1, 127), y1 = min(y0 + 1, 127), z1 = min(z0 + 1, 127);
    float wx = cx - fx, wy = cy - fy, wz = cz - fz;
    const float* ic = img + (size_t)c * (GRIDSZ * GRIDSZ * GRIDSZ);
    #define G(X, Y, Z) ic[((X) * GRIDSZ + (Y)) * GRIDSZ + (Z)]
    float c000 = G(x0, y0, z0), c001 = G(x0, y0, z1);
    float c010 = G(x0, y1, z0), c011 = G(x0, y1, z1);
    float c100 = G(x1, y0, z0), c101 = G(x1, y0, z1);
    float c110 = G(x1, y1, z0), c111 = G(x1, y1, z1);
    #undef G
    float c00 = c000 * (1.0f - wz) + c001 * wz;
    float c01 = c010 * (1.0f - wz) + c011 * wz;
    float c10 = c100 * (1.0f - wz) + c101 * wz;
    float c11 = c110 * (1.0f - wz) + c111 * wz;
    float r = (c00 * (1.0f - wy) + c01 * wy) * (1.0f - wx) +
              (c10 * (1.0f - wy) + c11 * wy) * wx;
    size_t row = (size_t)v * 20;
    feats[row + 3 + c] = r;
    if (c < 3) feats[row + c] = verts[v * 3 + c] * (1.0f / 128.0f);
    if (c == 0) feats[row + 19] = 0.0f;
}

// ---------------------------------------------------------------------------
// CSR gather-sum: nb[v] = sum over in-edges of x[src]. One thread per
// (vertex, float4 chunk); stride S floats, S % 4 == 0, pads are zeroed in x.
template <int S>
__global__ __launch_bounds__(256) void k_gather(const float* __restrict__ x,
                                                const int* __restrict__ rowStart,
                                                const int* __restrict__ csrSrc,
                                                float* __restrict__ nb, int nv) {
    constexpr int NCH = S / 4;
    int t = blockIdx.x * 256 + threadIdx.x;
    int v = t / NCH;
    if (v >= nv) return;
    int ch = t - v * NCH;
    int beg = rowStart[v];
    int end = rowStart[v + 1];
    float4 acc = make_float4(0.f, 0.f, 0.f, 0.f);
    for (int j = beg; j < end; ++j) {
        int s = csrSrc[j];
        float4 q = ((const float4*)(x + (size_t)s * S))[ch];
        acc.x += q.x; acc.y += q.y; acc.z += q.z; acc.w += q.w;
    }
    ((float4*)(nb + (size_t)v * S))[ch] = acc;
}

// ---------------------------------------------------------------------------
// Edge-conv dense part, load-amortized:
//   out[v][co] = act(x[v]@Ws + inv_deg[v]*(nb[v]@Wn) + b)
// Ws/Wn staged in LDS (zero-padded K). Each thread: VPT vertices x 8 outputs.
template <int CIN, int COUT, int SX, bool RELU>
__global__ __launch_bounds__(256) void k_layer(const float* __restrict__ x,
                                               const float* __restrict__ nb,
                                               const float* __restrict__ invdeg,
                                               const float* __restrict__ Ws,
                                               const float* __restrict__ Wn,
                                               const float* __restrict__ b,
                                               float* __restrict__ out, int nv) {
    constexpr int GR = COUT / 8;              // co-groups of 8 per vertex
    constexpr int VPT = 4;                    // vertices per thread
    constexpr int TPB = 256;
    constexpr int VPB = (TPB / GR) * VPT;     // vertices per block
    constexpr int KP = (CIN + 3) & ~3;        // K padded to multiple of 4
    __shared__ float ws_s[KP * COUT];
    __shared__ float wn_s[KP * COUT];
    for (int i = threadIdx.x; i < KP * COUT; i += TPB) {
        int k = i / COUT, c = i - k * COUT;
        float vs = 0.f, vn = 0.f;
        if (k < CIN) { vs = Ws[k * COUT + c]; vn = Wn[k * COUT + c]; }
        ws_s[i] = vs;
        wn_s[i] = vn;
    }
    __syncthreads();

    const int g = threadIdx.x % GR;
    const int co = g * 8;
    const int vt = threadIdx.x / GR;
    const int v0 = blockIdx.x * VPB + vt * VPT;

    float acc_s[VPT][8], acc_n[VPT][8];
    #pragma unroll
    for (int u = 0; u < VPT; ++u)
        #pragma unroll
        for (int i = 0; i < 8; ++i) { acc_s[u][i] = 0.f; acc_n[u][i] = 0.f; }

    for (int k = 0; k < KP; k += 4) {
        float4 xq[VPT], nq[VPT];
        #pragma unroll
        for (int u = 0; u < VPT; ++u) {
            int v = v0 + u;
            if (v < nv) {
                xq[u] = *(const float4*)(x + (size_t)v * SX + k);
                nq[u] = *(const float4*)(nb + (size_t)v * SX + k);
            } else {
                xq[u] = make_float4(0.f, 0.f, 0.f, 0.f);
                nq[u] = make_float4(0.f, 0.f, 0.f, 0.f);
            }
        }
        #pragma unroll
        for (int j = 0; j < 4; ++j) {
            const float4 wsa = *(const float4*)(ws_s + (k + j) * COUT + co);
            const float4 wsb = *(const float4*)(ws_s + (k + j) * COUT + co + 4);
            const float4 wna = *(const float4*)(wn_s + (k + j) * COUT + co);
            const float4 wnb = *(const float4*)(wn_s + (k + j) * COUT + co + 4);
            #pragma unroll
            for (int u = 0; u < VPT; ++u) {
                float xv = (j == 0) ? xq[u].x : (j == 1) ? xq[u].y : (j == 2) ? xq[u].z : xq[u].w;
                float nw = (j == 0) ? nq[u].x : (j == 1) ? nq[u].y : (j == 2) ? nq[u].z : nq[u].w;
                acc_s[u][0] += xv * wsa.x; acc_s[u][1] += xv * wsa.y;
                acc_s[u][2] += xv * wsa.z; acc_s[u][3] += xv * wsa.w;
                acc_s[u][4] += xv * wsb.x; acc_s[u][5] += xv * wsb.y;
                acc_s[u][6] += xv * wsb.z; acc_s[u][7] += xv * wsb.w;
                acc_n[u][0] += nw * wna.x; acc_n[u][1] += nw * wna.y;
                acc_n[u][2] += nw * wna.z; acc_n[u][3] += nw * wna.w;
                acc_n[u][4] += nw * wnb.x; acc_n[u][5] += nw * wnb.y;
                acc_n[u][6] += nw * wnb.z; acc_n[u][7] += nw * wnb.w;
            }
        }
    }

    #pragma unroll
    for (int u = 0; u < VPT; ++u) {
        int v = v0 + u;
        if (v >= nv) continue;
        float id = invdeg[v];
        float r[8];
        #pragma unroll
        for (int i = 0; i < 8; ++i) {
            float t = acc_s[u][i] + acc_n[u][i] * id + b[co + i];
            r[i] = (!RELU || t >= 0.f) ? t : SLOPE * t;
        }
        float4* op = (float4*)(out + (size_t)v * COUT + co);
        op[0] = make_float4(r[0], r[1], r[2], r[3]);
        op[1] = make_float4(r[4], r[5], r[6], r[7]);
    }
}

// Pre-multiply for layer 3: z[v][j] = h3[v] @ Wn3 (j<3), z stride 4, pad 0.
__global__ __launch_bounds__(256) void k_premul(const float* __restrict__ h,
                                                const float* __restrict__ wn,
                                                float* __restrict__ z, int nv) {
    __shared__ float w_s[64 * 3];
    if (threadIdx.x < 64 * 3) w_s[threadIdx.x] = wn[threadIdx.x];
    __syncthreads();
    int v = blockIdx.x * 256 + threadIdx.x;
    if (v >= nv) return;
    const float4* hr = (const float4*)(h + (size_t)v * 64);
    float a0 = 0.f, a1 = 0.f, a2 = 0.f;
    #pragma unroll
    for (int q = 0; q < 16; ++q) {
        float4 hv = hr[q];
        int k = q * 4;
        a0 += hv.x * w_s[k * 3 + 0] + hv.y * w_s[k * 3 + 3] + hv.z * w_s[k * 3 + 6] + hv.w * w_s[k * 3 + 9];
        a1 += hv.x * w_s[k * 3 + 1] + hv.y * w_s[k * 3 + 4] + hv.z * w_s[k * 3 + 7] + hv.w * w_s[k * 3 + 10];
        a2 += hv.x * w_s[k * 3 + 2] + hv.y * w_s[k * 3 + 5] + hv.z * w_s[k * 3 + 8] + hv.w * w_s[k * 3 + 11];
    }
    *((float4*)(z + (size_t)v * 4)) = make_float4(a0, a1, a2, 0.f);
}

// Final: out[v][j] = verts[v][j] + SCALE*(h3[v]@Ws3[:,j] + nb3[v][j]*inv_deg + b3[j])
__global__ __launch_bounds__(256) void k_final(const float* __restrict__ h,
                                               const float* __restrict__ nb,
                                               const float* __restrict__ invdeg,
                                               const float* __restrict__ ws,
                                               const float* __restrict__ b,
                                               const float* __restrict__ verts,
                                               float* __restrict__ out, int nv) {
    __shared__ float w_s[64 * 3];
    if (threadIdx.x < 64 * 3) w_s[threadIdx.x] = ws[threadIdx.x];
    __syncthreads();
    int v = blockIdx.x * 256 + threadIdx.x;
    if (v >= nv) return;
    const float4* hr = (const float4*)(h + (size_t)v * 64);
    float a0 = b[0], a1 = b[1], a2 = b[2];
    #pragma unroll
    for (int q = 0; q < 16; ++q) {
        float4 hv = hr[q];
        int k = q * 4;
        a0 += hv.x * w_s[k * 3 + 0] + hv.y * w_s[k * 3 + 3] + hv.z * w_s[k * 3 + 6] + hv.w * w_s[k * 3 + 9];
        a1 += hv.x * w_s[k * 3 + 1] + hv.y * w_s[k * 3 + 4] + hv.z * w_s[k * 3 + 7] + hv.w * w_s[k * 3 + 10];
        a2 += hv.x * w_s[k * 3 + 2] + hv.y * w_s[k * 3 + 5] + hv.z * w_s[k * 3 + 8] + hv.w * w_s[k * 3 + 11];
    }
    float id = invdeg[v];
    float4 nq = *((const float4*)(nb + (size_t)v * 4));
    a0 += nq.x * id; a1 += nq.y * id; a2 += nq.z * id;
    out[(size_t)v * 3 + 0] = verts[(size_t)v * 3 + 0] + SCALE * a0;
    out[(size_t)v * 3 + 1] = verts[(size_t)v * 3 + 1] + SCALE * a1;
    out[(size_t)v * 3 + 2] = verts[(size_t)v * 3 + 2] + SCALE * a2;
}

// ---------------------------------------------------------------------------
extern "C" void kernel_launch(void* const* d_in, const int* in_sizes, int n_in,
                              void* d_out, int out_size, void* d_ws, size_t ws_size,
                              hipStream_t stream) {
    const float* img   = (const float*)d_in[0];
    const float* verts = (const float*)d_in[1];
    const int*   esrc  = (const int*)d_in[2];
    const int*   edst  = (const int*)d_in[3];
    const float* ws0 = (const float*)d_in[4];
    const float* wn0 = (const float*)d_in[5];
    const float* b0  = (const float*)d_in[6];
    const float* ws1 = (const float*)d_in[7];
    const float* wn1 = (const float*)d_in[8];
    const float* b1  = (const float*)d_in[9];
    const float* ws2 = (const float*)d_in[10];
    const float* wn2 = (const float*)d_in[11];
    const float* b2  = (const float*)d_in[12];
    const float* ws3 = (const float*)d_in[13];
    const float* wn3 = (const float*)d_in[14];
    const float* b3  = (const float*)d_in[15];

    const int nv = in_sizes[1] / 3;
    const int ne = in_sizes[2];

    char* base = (char*)d_ws;
    size_t off = 0;
    auto alloc = [&](size_t bytes) -> void* {
        off = (off + 255) & ~(size_t)255;
        void* p = base + off;
        off += bytes;
        return p;
    };
    int*   deg      = (int*)alloc((size_t)nv * 4);
    float* invdeg   = (float*)alloc((size_t)nv * 4);
    int*   rowStart = (int*)alloc((size_t)(nv + 1) * 4);
    int*   cursor   = (int*)alloc((size_t)nv * 4);
    int*   partials = (int*)alloc(256 * 4);
    int*   csrSrc   = (int*)alloc((size_t)ne * 4);
    float* A        = (float*)alloc((size_t)nv * 64 * 4);  // feats(20) then h2(64)
    float* B        = (float*)alloc((size_t)nv * 64 * 4);  // h1(32) then h3(64)
    float* NB       = (float*)alloc((size_t)nv * 64 * 4);  // neighbor sums
    float* Z        = (float*)alloc((size_t)nv * 4 * 4);   // premultiplied layer-3

    auto blocks = [](long long n) { return (int)((n + 255) / 256); };
    const int np = (nv + SCAN_TILE - 1) / SCAN_TILE;

    // CSR build (multi-block scan)
    hipMemsetAsync(deg, 0, (size_t)nv * 4, stream);
    k_deg<<<blocks(ne), 256, 0, stream>>>(edst, deg, ne);
    k_scan1<<<np, 256, 0, stream>>>(deg, rowStart, partials, nv);
    k_scan2<<<1, 256, 0, stream>>>(partials, np);
    k_vinit<<<blocks(nv + 1), 256, 0, stream>>>(deg, rowStart, partials, invdeg, cursor, nv, ne);
    k_fill<<<blocks(ne), 256, 0, stream>>>(esrc, edst, cursor, csrSrc, ne);

    // Features
    k_sample<<<blocks((long long)nv * 16), 256, 0, stream>>>(img, verts, A, nv);

    // Layer 0: 19 -> 32
    k_gather<20><<<blocks((long long)nv * 5), 256, 0, stream>>>(A, rowStart, csrSrc, NB, nv);
    k_layer<19, 32, 20, true><<<(nv + 255) / 256, 256, 0, stream>>>(
        A, NB, invdeg, ws0, wn0, b0, B, nv);

    // Layer 1: 32 -> 64
    k_gather<32><<<blocks((long long)nv * 8), 256, 0, stream>>>(B, rowStart, csrSrc, NB, nv);
    k_layer<32, 64, 32, true><<<(nv + 127) / 128, 256, 0, stream>>>(
        B, NB, invdeg, ws1, wn1, b1, A, nv);

    // Layer 2: 64 -> 64
    k_gather<64><<<blocks((long long)nv * 16), 256, 0, stream>>>(A, rowStart, csrSrc, NB, nv);
    k_layer<64, 64, 64, true><<<(nv + 127) / 128, 256, 0, stream>>>(
        A, NB, invdeg, ws2, wn2, b2, B, nv);

    // Layer 3: pre-multiply by Wn3 (64->3), gather 4 floats, fuse final update
    k_premul<<<blocks(nv), 256, 0, stream>>>(B, wn3, Z, nv);
    k_gather<4><<<blocks(nv), 256, 0, stream>>>(Z, rowStart, csrSrc, NB, nv);
    k_final<<<blocks(nv), 256, 0, stream>>>(
        B, NB, invdeg, ws3, b3, verts, (float*)d_out, nv);
}

// Round 4
// 744.194 us; speedup vs baseline: 1.5503x; 1.0476x over previous
//
#include <hip/hip_runtime.h>

// Problem constants (from reference)
#define C_IMG 16
#define GRIDSZ 128
#define SLOPE 0.3f
#define SCALE 0.1f
#define SCAN_TILE 1024   // elements per scan-pass-1 block (256 thr x 4)

// bf16 helpers (manual, RNE pack / shift unpack)
__device__ __forceinline__ unsigned int bf16_pack2(float a, float b) {
    unsigned int ua = __float_as_uint(a);
    ua = (ua + 0x7FFFu + ((ua >> 16) & 1u)) >> 16;
    unsigned int ub = __float_as_uint(b);
    ub = (ub + 0x7FFFu + ((ub >> 16) & 1u)) >> 16;
    return ua | (ub << 16);
}
__device__ __forceinline__ float bf_lo(unsigned int u) { return __uint_as_float(u << 16); }
__device__ __forceinline__ float bf_hi(unsigned int u) { return __uint_as_float(u & 0xFFFF0000u); }

// ---------------------------------------------------------------------------
// Degree count (int atomics)
__global__ __launch_bounds__(256) void k_deg(const int* __restrict__ edst,
                                             int* __restrict__ deg, int ne) {
    int e = blockIdx.x * 256 + threadIdx.x;
    if (e >= ne) return;
    atomicAdd(&deg[edst[e]], 1);
}

// Multi-block scan pass 1
__global__ __launch_bounds__(256) void k_scan1(const int* __restrict__ deg,
                                               int* __restrict__ rowStart,
                                               int* __restrict__ partials, int nv) {
    __shared__ int ssum[256];
    const int tid = threadIdx.x;
    const int idx = blockIdx.x * SCAN_TILE + tid * 4;
    int d0 = 0, d1 = 0, d2 = 0, d3 = 0;
    if (idx + 3 < nv) {
        int4 q = *(const int4*)(deg + idx);
        d0 = q.x; d1 = q.y; d2 = q.z; d3 = q.w;
    } else {
        if (idx + 0 < nv) d0 = deg[idx + 0];
        if (idx + 1 < nv) d1 = deg[idx + 1];
        if (idx + 2 < nv) d2 = deg[idx + 2];
        if (idx + 3 < nv) d3 = deg[idx + 3];
    }
    const int tsum = d0 + d1 + d2 + d3;
    ssum[tid] = tsum;
    __syncthreads();
    #pragma unroll
    for (int off = 1; off < 256; off <<= 1) {
        int t = (tid >= off) ? ssum[tid - off] : 0;
        __syncthreads();
        ssum[tid] += t;
        __syncthreads();
    }
    const int excl = ssum[tid] - tsum;
    if (tid == 255) partials[blockIdx.x] = ssum[255];
    if (idx + 0 < nv) rowStart[idx + 0] = excl;
    if (idx + 1 < nv) rowStart[idx + 1] = excl + d0;
    if (idx + 2 < nv) rowStart[idx + 2] = excl + d0 + d1;
    if (idx + 3 < nv) rowStart[idx + 3] = excl + d0 + d1 + d2;
}

// Pass 2: exclusive scan of tile totals in place (np <= 256).
__global__ __launch_bounds__(256) void k_scan2(int* __restrict__ partials, int np) {
    __shared__ int buf[256];
    const int tid = threadIdx.x;
    const int v = (tid < np) ? partials[tid] : 0;
    buf[tid] = v;
    __syncthreads();
    #pragma unroll
    for (int off = 1; off < 256; off <<= 1) {
        int t = (tid >= off) ? buf[tid - off] : 0;
        __syncthreads();
        buf[tid] += t;
        __syncthreads();
    }
    if (tid < np) partials[tid] = buf[tid] - v;
}

// Pass 3 + vertex init
__global__ __launch_bounds__(256) void k_vinit(const int* __restrict__ deg,
                                               int* __restrict__ rowStart,
                                               const int* __restrict__ partials,
                                               float* __restrict__ invdeg,
                                               int* __restrict__ cursor,
                                               int nv, int ne) {
    int v = blockIdx.x * 256 + threadIdx.x;
    if (v > nv) return;
    if (v == nv) { rowStart[nv] = ne; return; }
    int rs = rowStart[v] + partials[v / SCAN_TILE];
    rowStart[v] = rs;
    cursor[v] = rs;
    int d = deg[v];
    invdeg[v] = 1.0f / (float)(d > 1 ? d : 1);
}

// CSR fill: csrSrc[pos] = src, grouped by dst
__global__ __launch_bounds__(256) void k_fill(const int* __restrict__ esrc,
                                              const int* __restrict__ edst,
                                              int* __restrict__ cursor,
                                              int* __restrict__ csrSrc, int ne) {
    int e = blockIdx.x * 256 + threadIdx.x;
    if (e >= ne) return;
    int pos = atomicAdd(&cursor[edst[e]], 1);
    csrSrc[pos] = esrc[e];
}

// ---------------------------------------------------------------------------
// Image transpose: img[16][128][128][128] fp32 -> timg[x][y][z][16] bf16.
// One thread per (xy, z0=4z chunk): 16 coalesced float4 reads (1 KB/wave/iter),
// register transpose, 4 x 32 B contiguous bf16 row writes (128 B/thread).
__global__ __launch_bounds__(256) void k_transpose(const float* __restrict__ img,
                                                   unsigned int* __restrict__ timg) {
    const int t = blockIdx.x * 256 + threadIdx.x;   // 128*128*32 total
    const int z0 = (t & 31) * 4;
    const int xy = t >> 5;
    float4 val[16];
    #pragma unroll
    for (int c = 0; c < 16; ++c)
        val[c] = *(const float4*)(img + (size_t)c * (GRIDSZ * GRIDSZ * GRIDSZ) + (size_t)xy * GRIDSZ + z0);
    // output row (xy*128 + z0 + j): 16 bf16 = 8 uints
    #pragma unroll
    for (int j = 0; j < 4; ++j) {
        uint4 o0, o1;
        float f[16];
        #pragma unroll
        for (int c = 0; c < 16; ++c)
            f[c] = (j == 0) ? val[c].x : (j == 1) ? val[c].y : (j == 2) ? val[c].z : val[c].w;
        o0.x = bf16_pack2(f[0], f[1]);  o0.y = bf16_pack2(f[2], f[3]);
        o0.z = bf16_pack2(f[4], f[5]);  o0.w = bf16_pack2(f[6], f[7]);
        o1.x = bf16_pack2(f[8], f[9]);  o1.y = bf16_pack2(f[10], f[11]);
        o1.z = bf16_pack2(f[12], f[13]); o1.w = bf16_pack2(f[14], f[15]);
        unsigned int* dst = timg + ((size_t)(xy * GRIDSZ + z0 + j)) * 8;
        *(uint4*)(dst + 0) = o0;
        *(uint4*)(dst + 4) = o1;
    }
}

// ---------------------------------------------------------------------------
// Trilinear sample from channel-last bf16 volume. 2 threads per vertex,
// 8 channels each: 8 corners x 16 B loads (dense 64 B lines).
// feats cols: 0..15 = channels, 16..18 = verts/128, 19 = pad(0).
__global__ __launch_bounds__(256) void k_sample(const unsigned int* __restrict__ timg,
                                                const float* __restrict__ verts,
                                                float* __restrict__ feats, int nv) {
    int t = blockIdx.x * 256 + threadIdx.x;
    int v = t >> 1;
    int q = t & 1;          // channel group: q*8 .. q*8+7
    if (v >= nv) return;
    float px = verts[v * 3 + 0];
    float py = verts[v * 3 + 1];
    float pz = verts[v * 3 + 2];
    float cx = fminf(fmaxf(px, 0.0f), 127.0f);
    float cy = fminf(fmaxf(py, 0.0f), 127.0f);
    float cz = fminf(fmaxf(pz, 0.0f), 127.0f);
    float fx = floorf(cx), fy = floorf(cy), fz = floorf(cz);
    int x0 = (int)fx, y0 = (int)fy, z0 = (int)fz;
    int x1 = min(x0 + 1, 127), y1 = min(y0 + 1, 127), z1 = min(z0 + 1, 127);
    float wx = cx - fx, wy = cy - fy, wz = cz - fz;
    const int qo = q * 4;   // uint offset within 8-uint row
    #define LD(X, Y, Z) (*(const uint4*)(timg + ((size_t)((((X) << 7) + (Y)) << 7) + (size_t)(Z)) * 8 + qo))
    uint4 f000 = LD(x0, y0, z0), f001 = LD(x0, y0, z1);
    uint4 f010 = LD(x0, y1, z0), f011 = LD(x0, y1, z1);
    uint4 f100 = LD(x1, y0, z0), f101 = LD(x1, y0, z1);
    uint4 f110 = LD(x1, y1, z0), f111 = LD(x1, y1, z1);
    #undef LD
    float r[8];
    const unsigned int* a000 = (const unsigned int*)&f000;
    const unsigned int* a001 = (const unsigned int*)&f001;
    const unsigned int* a010 = (const unsigned int*)&f010;
    const unsigned int* a011 = (const unsigned int*)&f011;
    const unsigned int* a100 = (const unsigned int*)&f100;
    const unsigned int* a101 = (const unsigned int*)&f101;
    const unsigned int* a110 = (const unsigned int*)&f110;
    const unsigned int* a111 = (const unsigned int*)&f111;
    #pragma unroll
    for (int u = 0; u < 4; ++u) {
        // low half (channel 2u), high half (channel 2u+1)
        float c00l = bf_lo(a000[u]) * (1.f - wz) + bf_lo(a001[u]) * wz;
        float c01l = bf_lo(a010[u]) * (1.f - wz) + bf_lo(a011[u]) * wz;
        float c10l = bf_lo(a100[u]) * (1.f - wz) + bf_lo(a101[u]) * wz;
        float c11l = bf_lo(a110[u]) * (1.f - wz) + bf_lo(a111[u]) * wz;
        r[2 * u] = (c00l * (1.f - wy) + c01l * wy) * (1.f - wx) +
                   (c10l * (1.f - wy) + c11l * wy) * wx;
        float c00h = bf_hi(a000[u]) * (1.f - wz) + bf_hi(a001[u]) * wz;
        float c01h = bf_hi(a010[u]) * (1.f - wz) + bf_hi(a011[u]) * wz;
        float c10h = bf_hi(a100[u]) * (1.f - wz) + bf_hi(a101[u]) * wz;
        float c11h = bf_hi(a110[u]) * (1.f - wz) + bf_hi(a111[u]) * wz;
        r[2 * u + 1] = (c00h * (1.f - wy) + c01h * wy) * (1.f - wx) +
                       (c10h * (1.f - wy) + c11h * wy) * wx;
    }
    float* row = feats + (size_t)v * 20 + q * 8;
    *(float4*)(row + 0) = make_float4(r[0], r[1], r[2], r[3]);
    *(float4*)(row + 4) = make_float4(r[4], r[5], r[6], r[7]);
    if (q == 0) {
        *(float4*)(feats + (size_t)v * 20 + 16) =
            make_float4(px * (1.0f / 128.0f), py * (1.0f / 128.0f), pz * (1.0f / 128.0f), 0.0f);
    }
}

// ---------------------------------------------------------------------------
// CSR gather-sum
template <int S>
__global__ __launch_bounds__(256) void k_gather(const float* __restrict__ x,
                                                const int* __restrict__ rowStart,
                                                const int* __restrict__ csrSrc,
                                                float* __restrict__ nb, int nv) {
    constexpr int NCH = S / 4;
    int t = blockIdx.x * 256 + threadIdx.x;
    int v = t / NCH;
    if (v >= nv) return;
    int ch = t - v * NCH;
    int beg = rowStart[v];
    int end = rowStart[v + 1];
    float4 acc = make_float4(0.f, 0.f, 0.f, 0.f);
    for (int j = beg; j < end; ++j) {
        int s = csrSrc[j];
        float4 q = ((const float4*)(x + (size_t)s * S))[ch];
        acc.x += q.x; acc.y += q.y; acc.z += q.z; acc.w += q.w;
    }
    ((float4*)(nb + (size_t)v * S))[ch] = acc;
}

// ---------------------------------------------------------------------------
// Edge-conv dense part. REMAP0: feats cols are [ch16, verts3, pad]; weight
// rows in reference order are [verts3, ch16] -> srcrow = k<16 ? k+3 : k-16.
template <int CIN, int COUT, int SX, bool RELU, bool REMAP0>
__global__ __launch_bounds__(256) void k_layer(const float* __restrict__ x,
                                               const float* __restrict__ nb,
                                               const float* __restrict__ invdeg,
                                               const float* __restrict__ Ws,
                                               const float* __restrict__ Wn,
                                               const float* __restrict__ b,
                                               float* __restrict__ out, int nv) {
    constexpr int GR = COUT / 8;              // co-groups of 8 per vertex
    constexpr int VPT = 4;                    // vertices per thread
    constexpr int TPB = 256;
    constexpr int VPB = (TPB / GR) * VPT;     // vertices per block
    constexpr int KP = (CIN + 3) & ~3;        // K padded to multiple of 4
    __shared__ float ws_s[KP * COUT];
    __shared__ float wn_s[KP * COUT];
    for (int i = threadIdx.x; i < KP * COUT; i += TPB) {
        int k = i / COUT, c = i - k * COUT;
        float vs = 0.f, vn = 0.f;
        if (k < CIN) {
            int sr = REMAP0 ? ((k < 16) ? (k + 3) : (k - 16)) : k;
            vs = Ws[sr * COUT + c];
            vn = Wn[sr * COUT + c];
        }
        ws_s[i] = vs;
        wn_s[i] = vn;
    }
    __syncthreads();

    const int g = threadIdx.x % GR;
    const int co = g * 8;
    const int vt = threadIdx.x / GR;
    const int v0 = blockIdx.x * VPB + vt * VPT;

    float acc_s[VPT][8], acc_n[VPT][8];
    #pragma unroll
    for (int u = 0; u < VPT; ++u)
        #pragma unroll
        for (int i = 0; i < 8; ++i) { acc_s[u][i] = 0.f; acc_n[u][i] = 0.f; }

    for (int k = 0; k < KP; k += 4) {
        float4 xq[VPT], nq[VPT];
        #pragma unroll
        for (int u = 0; u < VPT; ++u) {
            int v = v0 + u;
            if (v < nv) {
                xq[u] = *(const float4*)(x + (size_t)v * SX + k);
                nq[u] = *(const float4*)(nb + (size_t)v * SX + k);
            } else {
                xq[u] = make_float4(0.f, 0.f, 0.f, 0.f);
                nq[u] = make_float4(0.f, 0.f, 0.f, 0.f);
            }
        }
        #pragma unroll
        for (int j = 0; j < 4; ++j) {
            const float4 wsa = *(const float4*)(ws_s + (k + j) * COUT + co);
            const float4 wsb = *(const float4*)(ws_s + (k + j) * COUT + co + 4);
            const float4 wna = *(const float4*)(wn_s + (k + j) * COUT + co);
            const float4 wnb = *(const float4*)(wn_s + (k + j) * COUT + co + 4);
            #pragma unroll
            for (int u = 0; u < VPT; ++u) {
                float xv = (j == 0) ? xq[u].x : (j == 1) ? xq[u].y : (j == 2) ? xq[u].z : xq[u].w;
                float nw = (j == 0) ? nq[u].x : (j == 1) ? nq[u].y : (j == 2) ? nq[u].z : nq[u].w;
                acc_s[u][0] += xv * wsa.x; acc_s[u][1] += xv * wsa.y;
                acc_s[u][2] += xv * wsa.z; acc_s[u][3] += xv * wsa.w;
                acc_s[u][4] += xv * wsb.x; acc_s[u][5] += xv * wsb.y;
                acc_s[u][6] += xv * wsb.z; acc_s[u][7] += xv * wsb.w;
                acc_n[u][0] += nw * wna.x; acc_n[u][1] += nw * wna.y;
                acc_n[u][2] += nw * wna.z; acc_n[u][3] += nw * wna.w;
                acc_n[u][4] += nw * wnb.x; acc_n[u][5] += nw * wnb.y;
                acc_n[u][6] += nw * wnb.z; acc_n[u][7] += nw * wnb.w;
            }
        }
    }

    #pragma unroll
    for (int u = 0; u < VPT; ++u) {
        int v = v0 + u;
        if (v >= nv) continue;
        float id = invdeg[v];
        float r[8];
        #pragma unroll
        for (int i = 0; i < 8; ++i) {
            float t = acc_s[u][i] + acc_n[u][i] * id + b[co + i];
            r[i] = (!RELU || t >= 0.f) ? t : SLOPE * t;
        }
        float4* op = (float4*)(out + (size_t)v * COUT + co);
        op[0] = make_float4(r[0], r[1], r[2], r[3]);
        op[1] = make_float4(r[4], r[5], r[6], r[7]);
    }
}

// Pre-multiply for layer 3: z[v][j] = h3[v] @ Wn3 (j<3), z stride 4, pad 0.
__global__ __launch_bounds__(256) void k_premul(const float* __restrict__ h,
                                                const float* __restrict__ wn,
                                                float* __restrict__ z, int nv) {
    __shared__ float w_s[64 * 3];
    if (threadIdx.x < 64 * 3) w_s[threadIdx.x] = wn[threadIdx.x];
    __syncthreads();
    int v = blockIdx.x * 256 + threadIdx.x;
    if (v >= nv) return;
    const float4* hr = (const float4*)(h + (size_t)v * 64);
    float a0 = 0.f, a1 = 0.f, a2 = 0.f;
    #pragma unroll
    for (int q = 0; q < 16; ++q) {
        float4 hv = hr[q];
        int k = q * 4;
        a0 += hv.x * w_s[k * 3 + 0] + hv.y * w_s[k * 3 + 3] + hv.z * w_s[k * 3 + 6] + hv.w * w_s[k * 3 + 9];
        a1 += hv.x * w_s[k * 3 + 1] + hv.y * w_s[k * 3 + 4] + hv.z * w_s[k * 3 + 7] + hv.w * w_s[k * 3 + 10];
        a2 += hv.x * w_s[k * 3 + 2] + hv.y * w_s[k * 3 + 5] + hv.z * w_s[k * 3 + 8] + hv.w * w_s[k * 3 + 11];
    }
    *((float4*)(z + (size_t)v * 4)) = make_float4(a0, a1, a2, 0.f);
}

// Final: out = verts + SCALE*(h3@Ws3 + nb3*inv_deg + b3)
__global__ __launch_bounds__(256) void k_final(const float* __restrict__ h,
                                               const float* __restrict__ nb,
                                               const float* __restrict__ invdeg,
                                               const float* __restrict__ ws,
                                               const float* __restrict__ b,
                                               const float* __restrict__ verts,
                                               float* __restrict__ out, int nv) {
    __shared__ float w_s[64 * 3];
    if (threadIdx.x < 64 * 3) w_s[threadIdx.x] = ws[threadIdx.x];
    __syncthreads();
    int v = blockIdx.x * 256 + threadIdx.x;
    if (v >= nv) return;
    const float4* hr = (const float4*)(h + (size_t)v * 64);
    float a0 = b[0], a1 = b[1], a2 = b[2];
    #pragma unroll
    for (int q = 0; q < 16; ++q) {
        float4 hv = hr[q];
        int k = q * 4;
        a0 += hv.x * w_s[k * 3 + 0] + hv.y * w_s[k * 3 + 3] + hv.z * w_s[k * 3 + 6] + hv.w * w_s[k * 3 + 9];
        a1 += hv.x * w_s[k * 3 + 1] + hv.y * w_s[k * 3 + 4] + hv.z * w_s[k * 3 + 7] + hv.w * w_s[k * 3 + 10];
        a2 += hv.x * w_s[k * 3 + 2] + hv.y * w_s[k * 3 + 5] + hv.z * w_s[k * 3 + 8] + hv.w * w_s[k * 3 + 11];
    }
    float id = invdeg[v];
    float4 nq = *((const float4*)(nb + (size_t)v * 4));
    a0 += nq.x * id; a1 += nq.y * id; a2 += nq.z * id;
    out[(size_t)v * 3 + 0] = verts[(size_t)v * 3 + 0] + SCALE * a0;
    out[(size_t)v * 3 + 1] = verts[(size_t)v * 3 + 1] + SCALE * a1;
    out[(size_t)v * 3 + 2] = verts[(size_t)v * 3 + 2] + SCALE * a2;
}

// ---------------------------------------------------------------------------
extern "C" void kernel_launch(void* const* d_in, const int* in_sizes, int n_in,
                              void* d_out, int out_size, void* d_ws, size_t ws_size,
                              hipStream_t stream) {
    const float* img   = (const float*)d_in[0];
    const float* verts = (const float*)d_in[1];
    const int*   esrc  = (const int*)d_in[2];
    const int*   edst  = (const int*)d_in[3];
    const float* ws0 = (const float*)d_in[4];
    const float* wn0 = (const float*)d_in[5];
    const float* b0  = (const float*)d_in[6];
    const float* ws1 = (const float*)d_in[7];
    const float* wn1 = (const float*)d_in[8];
    const float* b1  = (const float*)d_in[9];
    const float* ws2 = (const float*)d_in[10];
    const float* wn2 = (const float*)d_in[11];
    const float* b2  = (const float*)d_in[12];
    const float* ws3 = (const float*)d_in[13];
    const float* wn3 = (const float*)d_in[14];
    const float* b3  = (const float*)d_in[15];

    const int nv = in_sizes[1] / 3;
    const int ne = in_sizes[2];

    char* base = (char*)d_ws;
    size_t off = 0;
    auto alloc = [&](size_t bytes) -> void* {
        off = (off + 255) & ~(size_t)255;
        void* p = base + off;
        off += bytes;
        return p;
    };
    int*   deg      = (int*)alloc((size_t)nv * 4);
    float* invdeg   = (float*)alloc((size_t)nv * 4);
    int*   rowStart = (int*)alloc((size_t)(nv + 1) * 4);
    int*   cursor   = (int*)alloc((size_t)nv * 4);
    int*   partials = (int*)alloc(256 * 4);
    int*   csrSrc   = (int*)alloc((size_t)ne * 4);
    float* A        = (float*)alloc((size_t)nv * 64 * 4);  // feats(20) then h2(64)
    float* B        = (float*)alloc((size_t)nv * 64 * 4);  // h1(32) then h3(64)
    float* NB       = (float*)alloc((size_t)nv * 64 * 4);  // neighbor sums
    float* Z        = (float*)alloc((size_t)nv * 4 * 4);   // premultiplied layer-3
    unsigned int* timg = (unsigned int*)alloc((size_t)GRIDSZ * GRIDSZ * GRIDSZ * 16 * 2); // bf16 channel-last, 67 MB

    auto blocks = [](long long n) { return (int)((n + 255) / 256); };
    const int np = (nv + SCAN_TILE - 1) / SCAN_TILE;

    // Image transpose (independent of CSR build)
    k_transpose<<<(GRIDSZ * GRIDSZ * 32) / 256, 256, 0, stream>>>(img, timg);

    // CSR build (multi-block scan)
    hipMemsetAsync(deg, 0, (size_t)nv * 4, stream);
    k_deg<<<blocks(ne), 256, 0, stream>>>(edst, deg, ne);
    k_scan1<<<np, 256, 0, stream>>>(deg, rowStart, partials, nv);
    k_scan2<<<1, 256, 0, stream>>>(partials, np);
    k_vinit<<<blocks(nv + 1), 256, 0, stream>>>(deg, rowStart, partials, invdeg, cursor, nv, ne);
    k_fill<<<blocks(ne), 256, 0, stream>>>(esrc, edst, cursor, csrSrc, ne);

    // Features (channel-last bf16 volume)
    k_sample<<<blocks((long long)nv * 2), 256, 0, stream>>>(timg, verts, A, nv);

    // Layer 0: 19 -> 32 (weight rows remapped for reordered feats)
    k_gather<20><<<blocks((long long)nv * 5), 256, 0, stream>>>(A, rowStart, csrSrc, NB, nv);
    k_layer<19, 32, 20, true, true><<<(nv + 255) / 256, 256, 0, stream>>>(
        A, NB, invdeg, ws0, wn0, b0, B, nv);

    // Layer 1: 32 -> 64
    k_gather<32><<<blocks((long long)nv * 8), 256, 0, stream>>>(B, rowStart, csrSrc, NB, nv);
    k_layer<32, 64, 32, true, false><<<(nv + 127) / 128, 256, 0, stream>>>(
        B, NB, invdeg, ws1, wn1, b1, A, nv);

    // Layer 2: 64 -> 64
    k_gather<64><<<blocks((long long)nv * 16), 256, 0, stream>>>(A, rowStart, csrSrc, NB, nv);
    k_layer<64, 64, 64, true, false><<<(nv + 127) / 128, 256, 0, stream>>>(
        A, NB, invdeg, ws2, wn2, b2, B, nv);

    // Layer 3: pre-multiply by Wn3 (64->3), gather 4 floats, fuse final update
    k_premul<<<blocks(nv), 256, 0, stream>>>(B, wn3, Z, nv);
    k_gather<4><<<blocks(nv), 256, 0, stream>>>(Z, rowStart, csrSrc, NB, nv);
    k_final<<<blocks(nv), 256, 0, stream>>>(
        B, NB, invdeg, ws3, b3, verts, (float*)d_out, nv);
}

// Round 5
// 671.034 us; speedup vs baseline: 1.7193x; 1.1090x over previous
//
#include <hip/hip_runtime.h>

// Problem constants (from reference)
#define C_IMG 16
#define GRIDSZ 128
#define SLOPE 0.3f
#define SCALE 0.1f
#define SCAN_TILE 1024   // elements per scan-pass-1 block (256 thr x 4)
#define EPB 4096         // edges per k_bucket block
#define BIN_CAP 16384    // max edges per 512-vertex bucket (mean 8192, sd ~90)

// bf16 helpers (manual, RNE pack / shift unpack)
__device__ __forceinline__ unsigned int bf16_pack2(float a, float b) {
    unsigned int ua = __float_as_uint(a);
    ua = (ua + 0x7FFFu + ((ua >> 16) & 1u)) >> 16;
    unsigned int ub = __float_as_uint(b);
    ub = (ub + 0x7FFFu + ((ub >> 16) & 1u)) >> 16;
    return ua | (ub << 16);
}
__device__ __forceinline__ float bf_lo(unsigned int u) { return __uint_as_float(u << 16); }
__device__ __forceinline__ float bf_hi(unsigned int u) { return __uint_as_float(u & 0xFFFF0000u); }

// ---------------------------------------------------------------------------
// Degree count (int atomics)
__global__ __launch_bounds__(256) void k_deg(const int* __restrict__ edst,
                                             int* __restrict__ deg, int ne) {
    int e = blockIdx.x * 256 + threadIdx.x;
    if (e >= ne) return;
    atomicAdd(&deg[edst[e]], 1);
}

// Multi-block scan pass 1
__global__ __launch_bounds__(256) void k_scan1(const int* __restrict__ deg,
                                               int* __restrict__ rowStart,
                                               int* __restrict__ partials, int nv) {
    __shared__ int ssum[256];
    const int tid = threadIdx.x;
    const int idx = blockIdx.x * SCAN_TILE + tid * 4;
    int d0 = 0, d1 = 0, d2 = 0, d3 = 0;
    if (idx + 3 < nv) {
        int4 q = *(const int4*)(deg + idx);
        d0 = q.x; d1 = q.y; d2 = q.z; d3 = q.w;
    } else {
        if (idx + 0 < nv) d0 = deg[idx + 0];
        if (idx + 1 < nv) d1 = deg[idx + 1];
        if (idx + 2 < nv) d2 = deg[idx + 2];
        if (idx + 3 < nv) d3 = deg[idx + 3];
    }
    const int tsum = d0 + d1 + d2 + d3;
    ssum[tid] = tsum;
    __syncthreads();
    #pragma unroll
    for (int off = 1; off < 256; off <<= 1) {
        int t = (tid >= off) ? ssum[tid - off] : 0;
        __syncthreads();
        ssum[tid] += t;
        __syncthreads();
    }
    const int excl = ssum[tid] - tsum;
    if (tid == 255) partials[blockIdx.x] = ssum[255];
    if (idx + 0 < nv) rowStart[idx + 0] = excl;
    if (idx + 1 < nv) rowStart[idx + 1] = excl + d0;
    if (idx + 2 < nv) rowStart[idx + 2] = excl + d0 + d1;
    if (idx + 3 < nv) rowStart[idx + 3] = excl + d0 + d1 + d2;
}

// Pass 2: exclusive scan of tile totals in place (np <= 256).
__global__ __launch_bounds__(256) void k_scan2(int* __restrict__ partials, int np) {
    __shared__ int buf[256];
    const int tid = threadIdx.x;
    const int v = (tid < np) ? partials[tid] : 0;
    buf[tid] = v;
    __syncthreads();
    #pragma unroll
    for (int off = 1; off < 256; off <<= 1) {
        int t = (tid >= off) ? buf[tid - off] : 0;
        __syncthreads();
        buf[tid] += t;
        __syncthreads();
    }
    if (tid < np) partials[tid] = buf[tid] - v;
}

// Pass 3 + vertex init
__global__ __launch_bounds__(256) void k_vinit(const int* __restrict__ deg,
                                               int* __restrict__ rowStart,
                                               const int* __restrict__ partials,
                                               float* __restrict__ invdeg,
                                               int* __restrict__ cursor,
                                               int nv, int ne) {
    int v = blockIdx.x * 256 + threadIdx.x;
    if (v > nv) return;
    if (v == nv) { rowStart[nv] = ne; return; }
    int rs = rowStart[v] + partials[v / SCAN_TILE];
    rowStart[v] = rs;
    cursor[v] = rs;
    int d = deg[v];
    invdeg[v] = 1.0f / (float)(d > 1 ? d : 1);
}

// Init per-bucket append cursors: bucketCursor[b] = rowStart[min(b*512, nv)]
__global__ __launch_bounds__(256) void k_binit(const int* __restrict__ rowStart,
                                               int* __restrict__ bucketCursor, int nv) {
    int t = threadIdx.x;
    bucketCursor[t] = rowStart[min(t << 9, nv)];
}

// Bucketing pass: group (dst,src) pairs by dst>>9 into per-bucket global
// regions with dense (coalesced-run) writes. LDS-staged local grouping.
__global__ __launch_bounds__(256) void k_bucket(const int* __restrict__ esrc,
                                                const int* __restrict__ edst,
                                                int* __restrict__ bucketCursor,
                                                uint2* __restrict__ pairs, int ne) {
    __shared__ unsigned int hist[256];
    __shared__ unsigned int pref[256];
    __shared__ unsigned int curs[256];
    __shared__ unsigned int gbase[256];
    __shared__ uint2 stage[EPB];
    const int tid = threadIdx.x;
    const int base = blockIdx.x * EPB;
    const int n = min(EPB, ne - base);
    hist[tid] = 0;
    __syncthreads();
    for (int i = tid; i < n; i += 256)
        atomicAdd(&hist[((unsigned)edst[base + i]) >> 9], 1u);
    __syncthreads();
    const unsigned int h = hist[tid];
    pref[tid] = h;
    __syncthreads();
    #pragma unroll
    for (int off = 1; off < 256; off <<= 1) {
        unsigned int t = (tid >= off) ? pref[tid - off] : 0;
        __syncthreads();
        pref[tid] += t;
        __syncthreads();
    }
    const unsigned int excl = pref[tid] - h;
    gbase[tid] = h ? (unsigned int)atomicAdd(&bucketCursor[tid], (int)h) : 0u;
    __syncthreads();          // everyone done reading pref as inclusive scan
    pref[tid] = excl;
    curs[tid] = excl;
    __syncthreads();
    for (int i = tid; i < n; i += 256) {
        int d = edst[base + i];
        int s = esrc[base + i];
        unsigned int p = atomicAdd(&curs[((unsigned)d) >> 9], 1u);
        stage[p] = make_uint2((unsigned)d, (unsigned)s);
    }
    __syncthreads();
    for (int i = tid; i < n; i += 256) {
        uint2 pr = stage[i];
        unsigned int b = pr.x >> 9;
        pairs[gbase[b] + (unsigned)i - pref[b]] = pr;
    }
}

// Within-bucket scatter: one block per bucket; LDS cursors + LDS out buffer,
// all global reads/writes coalesced.
__global__ __launch_bounds__(256) void k_binsort(const uint2* __restrict__ pairs,
                                                 const int* __restrict__ rowStart,
                                                 int* __restrict__ cursorGlobal,
                                                 int* __restrict__ csrSrc, int nv) {
    __shared__ int cur[512];
    __shared__ int outbuf[BIN_CAP];
    const int tid = threadIdx.x;
    const int b = blockIdx.x;
    const int vbase = b << 9;
    if (vbase >= nv) return;
    const int vend = min(vbase + 512, nv);
    const int gs = rowStart[vbase];
    const int ge = rowStart[vend];
    const int count = ge - gs;
    for (int v = vbase + tid; v < vend; v += 256) cur[v - vbase] = rowStart[v] - gs;
    __syncthreads();
    if (count <= BIN_CAP) {
        for (int i = tid; i < count; i += 256) {
            uint2 p = pairs[gs + i];
            int pos = atomicAdd(&cur[p.x - (unsigned)vbase], 1);
            outbuf[pos] = (int)p.y;
        }
        __syncthreads();
        for (int i = tid; i < count; i += 256) csrSrc[gs + i] = outbuf[i];
    } else {
        // statistically unreachable fallback (correctness-preserving)
        for (int i = tid; i < count; i += 256) {
            uint2 p = pairs[gs + i];
            int pos = atomicAdd(&cursorGlobal[p.x], 1);
            csrSrc[pos] = (int)p.y;
        }
    }
}

// ---------------------------------------------------------------------------
// Image transpose: img[16][128][128][128] fp32 -> timg[x][y][z][16] bf16.
__global__ __launch_bounds__(256) void k_transpose(const float* __restrict__ img,
                                                   unsigned int* __restrict__ timg) {
    const int t = blockIdx.x * 256 + threadIdx.x;   // 128*128*32 total
    const int z0 = (t & 31) * 4;
    const int xy = t >> 5;
    float4 val[16];
    #pragma unroll
    for (int c = 0; c < 16; ++c)
        val[c] = *(const float4*)(img + (size_t)c * (GRIDSZ * GRIDSZ * GRIDSZ) + (size_t)xy * GRIDSZ + z0);
    #pragma unroll
    for (int j = 0; j < 4; ++j) {
        uint4 o0, o1;
        float f[16];
        #pragma unroll
        for (int c = 0; c < 16; ++c)
            f[c] = (j == 0) ? val[c].x : (j == 1) ? val[c].y : (j == 2) ? val[c].z : val[c].w;
        o0.x = bf16_pack2(f[0], f[1]);  o0.y = bf16_pack2(f[2], f[3]);
        o0.z = bf16_pack2(f[4], f[5]);  o0.w = bf16_pack2(f[6], f[7]);
        o1.x = bf16_pack2(f[8], f[9]);  o1.y = bf16_pack2(f[10], f[11]);
        o1.z = bf16_pack2(f[12], f[13]); o1.w = bf16_pack2(f[14], f[15]);
        unsigned int* dst = timg + ((size_t)(xy * GRIDSZ + z0 + j)) * 8;
        *(uint4*)(dst + 0) = o0;
        *(uint4*)(dst + 4) = o1;
    }
}

// ---------------------------------------------------------------------------
// Trilinear sample from channel-last bf16 volume. 2 threads per vertex.
// feats cols: 0..15 = channels, 16..18 = verts/128, 19 = pad(0).
__global__ __launch_bounds__(256) void k_sample(const unsigned int* __restrict__ timg,
                                                const float* __restrict__ verts,
                                                float* __restrict__ feats, int nv) {
    int t = blockIdx.x * 256 + threadIdx.x;
    int v = t >> 1;
    int q = t & 1;          // channel group: q*8 .. q*8+7
    if (v >= nv) return;
    float px = verts[v * 3 + 0];
    float py = verts[v * 3 + 1];
    float pz = verts[v * 3 + 2];
    float cx = fminf(fmaxf(px, 0.0f), 127.0f);
    float cy = fminf(fmaxf(py, 0.0f), 127.0f);
    float cz = fminf(fmaxf(pz, 0.0f), 127.0f);
    float fx = floorf(cx), fy = floorf(cy), fz = floorf(cz);
    int x0 = (int)fx, y0 = (int)fy, z0 = (int)fz;
    int x1 = min(x0 + 1, 127), y1 = min(y0 + 1, 127), z1 = min(z0 + 1, 127);
    float wx = cx - fx, wy = cy - fy, wz = cz - fz;
    const int qo = q * 4;   // uint offset within 8-uint row
    #define LD(X, Y, Z) (*(const uint4*)(timg + ((size_t)((((X) << 7) + (Y)) << 7) + (size_t)(Z)) * 8 + qo))
    uint4 f000 = LD(x0, y0, z0), f001 = LD(x0, y0, z1);
    uint4 f010 = LD(x0, y1, z0), f011 = LD(x0, y1, z1);
    uint4 f100 = LD(x1, y0, z0), f101 = LD(x1, y0, z1);
    uint4 f110 = LD(x1, y1, z0), f111 = LD(x1, y1, z1);
    #undef LD
    float r[8];
    const unsigned int* a000 = (const unsigned int*)&f000;
    const unsigned int* a001 = (const unsigned int*)&f001;
    const unsigned int* a010 = (const unsigned int*)&f010;
    const unsigned int* a011 = (const unsigned int*)&f011;
    const unsigned int* a100 = (const unsigned int*)&f100;
    const unsigned int* a101 = (const unsigned int*)&f101;
    const unsigned int* a110 = (const unsigned int*)&f110;
    const unsigned int* a111 = (const unsigned int*)&f111;
    #pragma unroll
    for (int u = 0; u < 4; ++u) {
        float c00l = bf_lo(a000[u]) * (1.f - wz) + bf_lo(a001[u]) * wz;
        float c01l = bf_lo(a010[u]) * (1.f - wz) + bf_lo(a011[u]) * wz;
        float c10l = bf_lo(a100[u]) * (1.f - wz) + bf_lo(a101[u]) * wz;
        float c11l = bf_lo(a110[u]) * (1.f - wz) + bf_lo(a111[u]) * wz;
        r[2 * u] = (c00l * (1.f - wy) + c01l * wy) * (1.f - wx) +
                   (c10l * (1.f - wy) + c11l * wy) * wx;
        float c00h = bf_hi(a000[u]) * (1.f - wz) + bf_hi(a001[u]) * wz;
        float c01h = bf_hi(a010[u]) * (1.f - wz) + bf_hi(a011[u]) * wz;
        float c10h = bf_hi(a100[u]) * (1.f - wz) + bf_hi(a101[u]) * wz;
        float c11h = bf_hi(a110[u]) * (1.f - wz) + bf_hi(a111[u]) * wz;
        r[2 * u + 1] = (c00h * (1.f - wy) + c01h * wy) * (1.f - wx) +
                       (c10h * (1.f - wy) + c11h * wy) * wx;
    }
    float* row = feats + (size_t)v * 20 + q * 8;
    *(float4*)(row + 0) = make_float4(r[0], r[1], r[2], r[3]);
    *(float4*)(row + 4) = make_float4(r[4], r[5], r[6], r[7]);
    if (q == 0) {
        *(float4*)(feats + (size_t)v * 20 + 16) =
            make_float4(px * (1.0f / 128.0f), py * (1.0f / 128.0f), pz * (1.0f / 128.0f), 0.0f);
    }
}

// ---------------------------------------------------------------------------
// CSR gather-sum
template <int S>
__global__ __launch_bounds__(256) void k_gather(const float* __restrict__ x,
                                                const int* __restrict__ rowStart,
                                                const int* __restrict__ csrSrc,
                                                float* __restrict__ nb, int nv) {
    constexpr int NCH = S / 4;
    int t = blockIdx.x * 256 + threadIdx.x;
    int v = t / NCH;
    if (v >= nv) return;
    int ch = t - v * NCH;
    int beg = rowStart[v];
    int end = rowStart[v + 1];
    float4 acc = make_float4(0.f, 0.f, 0.f, 0.f);
    for (int j = beg; j < end; ++j) {
        int s = csrSrc[j];
        float4 q = ((const float4*)(x + (size_t)s * S))[ch];
        acc.x += q.x; acc.y += q.y; acc.z += q.z; acc.w += q.w;
    }
    ((float4*)(nb + (size_t)v * S))[ch] = acc;
}

// ---------------------------------------------------------------------------
// Edge-conv dense part. REMAP0: feats cols are [ch16, verts3, pad]; weight
// rows in reference order are [verts3, ch16] -> srcrow = k<16 ? k+3 : k-16.
template <int CIN, int COUT, int SX, bool RELU, bool REMAP0>
__global__ __launch_bounds__(256) void k_layer(const float* __restrict__ x,
                                               const float* __restrict__ nb,
                                               const float* __restrict__ invdeg,
                                               const float* __restrict__ Ws,
                                               const float* __restrict__ Wn,
                                               const float* __restrict__ b,
                                               float* __restrict__ out, int nv) {
    constexpr int GR = COUT / 8;              // co-groups of 8 per vertex
    constexpr int VPT = 4;                    // vertices per thread
    constexpr int TPB = 256;
    constexpr int VPB = (TPB / GR) * VPT;     // vertices per block
    constexpr int KP = (CIN + 3) & ~3;        // K padded to multiple of 4
    __shared__ float ws_s[KP * COUT];
    __shared__ float wn_s[KP * COUT];
    for (int i = threadIdx.x; i < KP * COUT; i += TPB) {
        int k = i / COUT, c = i - k * COUT;
        float vs = 0.f, vn = 0.f;
        if (k < CIN) {
            int sr = REMAP0 ? ((k < 16) ? (k + 3) : (k - 16)) : k;
            vs = Ws[sr * COUT + c];
            vn = Wn[sr * COUT + c];
        }
        ws_s[i] = vs;
        wn_s[i] = vn;
    }
    __syncthreads();

    const int g = threadIdx.x % GR;
    const int co = g * 8;
    const int vt = threadIdx.x / GR;
    const int v0 = blockIdx.x * VPB + vt * VPT;

    float acc_s[VPT][8], acc_n[VPT][8];
    #pragma unroll
    for (int u = 0; u < VPT; ++u)
        #pragma unroll
        for (int i = 0; i < 8; ++i) { acc_s[u][i] = 0.f; acc_n[u][i] = 0.f; }

    for (int k = 0; k < KP; k += 4) {
        float4 xq[VPT], nq[VPT];
        #pragma unroll
        for (int u = 0; u < VPT; ++u) {
            int v = v0 + u;
            if (v < nv) {
                xq[u] = *(const float4*)(x + (size_t)v * SX + k);
                nq[u] = *(const float4*)(nb + (size_t)v * SX + k);
            } else {
                xq[u] = make_float4(0.f, 0.f, 0.f, 0.f);
                nq[u] = make_float4(0.f, 0.f, 0.f, 0.f);
            }
        }
        #pragma unroll
        for (int j = 0; j < 4; ++j) {
            const float4 wsa = *(const float4*)(ws_s + (k + j) * COUT + co);
            const float4 wsb = *(const float4*)(ws_s + (k + j) * COUT + co + 4);
            const float4 wna = *(const float4*)(wn_s + (k + j) * COUT + co);
            const float4 wnb = *(const float4*)(wn_s + (k + j) * COUT + co + 4);
            #pragma unroll
            for (int u = 0; u < VPT; ++u) {
                float xv = (j == 0) ? xq[u].x : (j == 1) ? xq[u].y : (j == 2) ? xq[u].z : xq[u].w;
                float nw = (j == 0) ? nq[u].x : (j == 1) ? nq[u].y : (j == 2) ? nq[u].z : nq[u].w;
                acc_s[u][0] += xv * wsa.x; acc_s[u][1] += xv * wsa.y;
                acc_s[u][2] += xv * wsa.z; acc_s[u][3] += xv * wsa.w;
                acc_s[u][4] += xv * wsb.x; acc_s[u][5] += xv * wsb.y;
                acc_s[u][6] += xv * wsb.z; acc_s[u][7] += xv * wsb.w;
                acc_n[u][0] += nw * wna.x; acc_n[u][1] += nw * wna.y;
                acc_n[u][2] += nw * wna.z; acc_n[u][3] += nw * wna.w;
                acc_n[u][4] += nw * wnb.x; acc_n[u][5] += nw * wnb.y;
                acc_n[u][6] += nw * wnb.z; acc_n[u][7] += nw * wnb.w;
            }
        }
    }

    #pragma unroll
    for (int u = 0; u < VPT; ++u) {
        int v = v0 + u;
        if (v >= nv) continue;
        float id = invdeg[v];
        float r[8];
        #pragma unroll
        for (int i = 0; i < 8; ++i) {
            float t = acc_s[u][i] + acc_n[u][i] * id + b[co + i];
            r[i] = (!RELU || t >= 0.f) ? t : SLOPE * t;
        }
        float4* op = (float4*)(out + (size_t)v * COUT + co);
        op[0] = make_float4(r[0], r[1], r[2], r[3]);
        op[1] = make_float4(r[4], r[5], r[6], r[7]);
    }
}

// Pre-multiply for layer 3: z[v][j] = h3[v] @ Wn3 (j<3), z stride 4, pad 0.
__global__ __launch_bounds__(256) void k_premul(const float* __restrict__ h,
                                                const float* __restrict__ wn,
                                                float* __restrict__ z, int nv) {
    __shared__ float w_s[64 * 3];
    if (threadIdx.x < 64 * 3) w_s[threadIdx.x] = wn[threadIdx.x];
    __syncthreads();
    int v = blockIdx.x * 256 + threadIdx.x;
    if (v >= nv) return;
    const float4* hr = (const float4*)(h + (size_t)v * 64);
    float a0 = 0.f, a1 = 0.f, a2 = 0.f;
    #pragma unroll
    for (int q = 0; q < 16; ++q) {
        float4 hv = hr[q];
        int k = q * 4;
        a0 += hv.x * w_s[k * 3 + 0] + hv.y * w_s[k * 3 + 3] + hv.z * w_s[k * 3 + 6] + hv.w * w_s[k * 3 + 9];
        a1 += hv.x * w_s[k * 3 + 1] + hv.y * w_s[k * 3 + 4] + hv.z * w_s[k * 3 + 7] + hv.w * w_s[k * 3 + 10];
        a2 += hv.x * w_s[k * 3 + 2] + hv.y * w_s[k * 3 + 5] + hv.z * w_s[k * 3 + 8] + hv.w * w_s[k * 3 + 11];
    }
    *((float4*)(z + (size_t)v * 4)) = make_float4(a0, a1, a2, 0.f);
}

// Final: out = verts + SCALE*(h3@Ws3 + nb3*inv_deg + b3)
__global__ __launch_bounds__(256) void k_final(const float* __restrict__ h,
                                               const float* __restrict__ nb,
                                               const float* __restrict__ invdeg,
                                               const float* __restrict__ ws,
                                               const float* __restrict__ b,
                                               const float* __restrict__ verts,
                                               float* __restrict__ out, int nv) {
    __shared__ float w_s[64 * 3];
    if (threadIdx.x < 64 * 3) w_s[threadIdx.x] = ws[threadIdx.x];
    __syncthreads();
    int v = blockIdx.x * 256 + threadIdx.x;
    if (v >= nv) return;
    const float4* hr = (const float4*)(h + (size_t)v * 64);
    float a0 = b[0], a1 = b[1], a2 = b[2];
    #pragma unroll
    for (int q = 0; q < 16; ++q) {
        float4 hv = hr[q];
        int k = q * 4;
        a0 += hv.x * w_s[k * 3 + 0] + hv.y * w_s[k * 3 + 3] + hv.z * w_s[k * 3 + 6] + hv.w * w_s[k * 3 + 9];
        a1 += hv.x * w_s[k * 3 + 1] + hv.y * w_s[k * 3 + 4] + hv.z * w_s[k * 3 + 7] + hv.w * w_s[k * 3 + 10];
        a2 += hv.x * w_s[k * 3 + 2] + hv.y * w_s[k * 3 + 5] + hv.z * w_s[k * 3 + 8] + hv.w * w_s[k * 3 + 11];
    }
    float id = invdeg[v];
    float4 nq = *((const float4*)(nb + (size_t)v * 4));
    a0 += nq.x * id; a1 += nq.y * id; a2 += nq.z * id;
    out[(size_t)v * 3 + 0] = verts[(size_t)v * 3 + 0] + SCALE * a0;
    out[(size_t)v * 3 + 1] = verts[(size_t)v * 3 + 1] + SCALE * a1;
    out[(size_t)v * 3 + 2] = verts[(size_t)v * 3 + 2] + SCALE * a2;
}

// ---------------------------------------------------------------------------
extern "C" void kernel_launch(void* const* d_in, const int* in_sizes, int n_in,
                              void* d_out, int out_size, void* d_ws, size_t ws_size,
                              hipStream_t stream) {
    const float* img   = (const float*)d_in[0];
    const float* verts = (const float*)d_in[1];
    const int*   esrc  = (const int*)d_in[2];
    const int*   edst  = (const int*)d_in[3];
    const float* ws0 = (const float*)d_in[4];
    const float* wn0 = (const float*)d_in[5];
    const float* b0  = (const float*)d_in[6];
    const float* ws1 = (const float*)d_in[7];
    const float* wn1 = (const float*)d_in[8];
    const float* b1  = (const float*)d_in[9];
    const float* ws2 = (const float*)d_in[10];
    const float* wn2 = (const float*)d_in[11];
    const float* b2  = (const float*)d_in[12];
    const float* ws3 = (const float*)d_in[13];
    const float* wn3 = (const float*)d_in[14];
    const float* b3  = (const float*)d_in[15];

    const int nv = in_sizes[1] / 3;
    const int ne = in_sizes[2];

    char* base = (char*)d_ws;
    size_t off = 0;
    auto alloc = [&](size_t bytes) -> void* {
        off = (off + 255) & ~(size_t)255;
        void* p = base + off;
        off += bytes;
        return p;
    };
    int*   deg      = (int*)alloc((size_t)nv * 4);
    float* invdeg   = (float*)alloc((size_t)nv * 4);
    int*   rowStart = (int*)alloc((size_t)(nv + 1) * 4);
    int*   cursor   = (int*)alloc((size_t)nv * 4);
    int*   partials = (int*)alloc(256 * 4);
    int*   bucketCursor = (int*)alloc(256 * 4);
    int*   csrSrc   = (int*)alloc((size_t)ne * 4);
    float* A        = (float*)alloc((size_t)nv * 64 * 4);  // feats(20) then h2(64)
    float* B        = (float*)alloc((size_t)nv * 64 * 4);  // h1(32) then h3(64)
    float* NB       = (float*)alloc((size_t)nv * 64 * 4);  // neighbor sums
    float* Z        = (float*)alloc((size_t)nv * 4 * 4);   // premultiplied layer-3
    unsigned int* timg = (unsigned int*)alloc((size_t)GRIDSZ * GRIDSZ * GRIDSZ * 16 * 2); // bf16 channel-last
    uint2* pairs = (uint2*)NB;   // alias: NB unused until gathers (needs ne*8 <= nv*256 B)

    auto blocks = [](long long n) { return (int)((n + 255) / 256); };
    const int np = (nv + SCAN_TILE - 1) / SCAN_TILE;
    const int nbuckets = (nv + 511) >> 9;

    // Image transpose (independent of CSR build)
    k_transpose<<<(GRIDSZ * GRIDSZ * 32) / 256, 256, 0, stream>>>(img, timg);

    // CSR build: degree -> scan -> bucketed counting sort
    hipMemsetAsync(deg, 0, (size_t)nv * 4, stream);
    k_deg<<<blocks(ne), 256, 0, stream>>>(edst, deg, ne);
    k_scan1<<<np, 256, 0, stream>>>(deg, rowStart, partials, nv);
    k_scan2<<<1, 256, 0, stream>>>(partials, np);
    k_vinit<<<blocks(nv + 1), 256, 0, stream>>>(deg, rowStart, partials, invdeg, cursor, nv, ne);
    k_binit<<<1, 256, 0, stream>>>(rowStart, bucketCursor, nv);
    k_bucket<<<(ne + EPB - 1) / EPB, 256, 0, stream>>>(esrc, edst, bucketCursor, pairs, ne);
    k_binsort<<<nbuckets, 256, 0, stream>>>(pairs, rowStart, cursor, csrSrc, nv);

    // Features (channel-last bf16 volume)
    k_sample<<<blocks((long long)nv * 2), 256, 0, stream>>>(timg, verts, A, nv);

    // Layer 0: 19 -> 32 (weight rows remapped for reordered feats)
    k_gather<20><<<blocks((long long)nv * 5), 256, 0, stream>>>(A, rowStart, csrSrc, NB, nv);
    k_layer<19, 32, 20, true, true><<<(nv + 255) / 256, 256, 0, stream>>>(
        A, NB, invdeg, ws0, wn0, b0, B, nv);

    // Layer 1: 32 -> 64
    k_gather<32><<<blocks((long long)nv * 8), 256, 0, stream>>>(B, rowStart, csrSrc, NB, nv);
    k_layer<32, 64, 32, true, false><<<(nv + 127) / 128, 256, 0, stream>>>(
        B, NB, invdeg, ws1, wn1, b1, A, nv);

    // Layer 2: 64 -> 64
    k_gather<64><<<blocks((long long)nv * 16), 256, 0, stream>>>(A, rowStart, csrSrc, NB, nv);
    k_layer<64, 64, 64, true, false><<<(nv + 127) / 128, 256, 0, stream>>>(
        A, NB, invdeg, ws2, wn2, b2, B, nv);

    // Layer 3: pre-multiply by Wn3 (64->3), gather 4 floats, fuse final update
    k_premul<<<blocks(nv), 256, 0, stream>>>(B, wn3, Z, nv);
    k_gather<4><<<blocks(nv), 256, 0, stream>>>(Z, rowStart, csrSrc, NB, nv);
    k_final<<<blocks(nv), 256, 0, stream>>>(
        B, NB, invdeg, ws3, b3, verts, (float*)d_out, nv);
}

// Round 6
// 642.168 us; speedup vs baseline: 1.7966x; 1.0450x over previous
//
#include <hip/hip_runtime.h>

// Problem constants (from reference)
#define C_IMG 16
#define GRIDSZ 128
#define VOL (GRIDSZ * GRIDSZ * GRIDSZ)
#define SLOPE 0.3f
#define SCALE 0.1f
#define SCAN_TILE 1024   // elements per scan-pass-1 block (256 thr x 4)
#define EPB 4096         // edges per k_bucket block
#define BIN_CAP 16384    // max edges per 512-vertex bucket (mean 8192, sd ~90)

// bf16 helpers (manual, RNE pack / shift unpack)
__device__ __forceinline__ unsigned int bf16_pack2(float a, float b) {
    unsigned int ua = __float_as_uint(a);
    ua = (ua + 0x7FFFu + ((ua >> 16) & 1u)) >> 16;
    unsigned int ub = __float_as_uint(b);
    ub = (ub + 0x7FFFu + ((ub >> 16) & 1u)) >> 16;
    return ua | (ub << 16);
}
__device__ __forceinline__ float bf_lo(unsigned int u) { return __uint_as_float(u << 16); }
__device__ __forceinline__ float bf_hi(unsigned int u) { return __uint_as_float(u & 0xFFFF0000u); }

// ---------------------------------------------------------------------------
// Degree count (int atomics)
__global__ __launch_bounds__(256) void k_deg(const int* __restrict__ edst,
                                             int* __restrict__ deg, int ne) {
    int e = blockIdx.x * 256 + threadIdx.x;
    if (e >= ne) return;
    atomicAdd(&deg[edst[e]], 1);
}

// Multi-block scan pass 1
__global__ __launch_bounds__(256) void k_scan1(const int* __restrict__ deg,
                                               int* __restrict__ rowStart,
                                               int* __restrict__ partials, int nv) {
    __shared__ int ssum[256];
    const int tid = threadIdx.x;
    const int idx = blockIdx.x * SCAN_TILE + tid * 4;
    int d0 = 0, d1 = 0, d2 = 0, d3 = 0;
    if (idx + 3 < nv) {
        int4 q = *(const int4*)(deg + idx);
        d0 = q.x; d1 = q.y; d2 = q.z; d3 = q.w;
    } else {
        if (idx + 0 < nv) d0 = deg[idx + 0];
        if (idx + 1 < nv) d1 = deg[idx + 1];
        if (idx + 2 < nv) d2 = deg[idx + 2];
        if (idx + 3 < nv) d3 = deg[idx + 3];
    }
    const int tsum = d0 + d1 + d2 + d3;
    ssum[tid] = tsum;
    __syncthreads();
    #pragma unroll
    for (int off = 1; off < 256; off <<= 1) {
        int t = (tid >= off) ? ssum[tid - off] : 0;
        __syncthreads();
        ssum[tid] += t;
        __syncthreads();
    }
    const int excl = ssum[tid] - tsum;
    if (tid == 255) partials[blockIdx.x] = ssum[255];
    if (idx + 0 < nv) rowStart[idx + 0] = excl;
    if (idx + 1 < nv) rowStart[idx + 1] = excl + d0;
    if (idx + 2 < nv) rowStart[idx + 2] = excl + d0 + d1;
    if (idx + 3 < nv) rowStart[idx + 3] = excl + d0 + d1 + d2;
}

// Pass 2: exclusive scan of tile totals in place (np <= 256).
__global__ __launch_bounds__(256) void k_scan2(int* __restrict__ partials, int np) {
    __shared__ int buf[256];
    const int tid = threadIdx.x;
    const int v = (tid < np) ? partials[tid] : 0;
    buf[tid] = v;
    __syncthreads();
    #pragma unroll
    for (int off = 1; off < 256; off <<= 1) {
        int t = (tid >= off) ? buf[tid - off] : 0;
        __syncthreads();
        buf[tid] += t;
        __syncthreads();
    }
    if (tid < np) partials[tid] = buf[tid] - v;
}

// Pass 3 + vertex init
__global__ __launch_bounds__(256) void k_vinit(const int* __restrict__ deg,
                                               int* __restrict__ rowStart,
                                               const int* __restrict__ partials,
                                               float* __restrict__ invdeg,
                                               int* __restrict__ cursor,
                                               int nv, int ne) {
    int v = blockIdx.x * 256 + threadIdx.x;
    if (v > nv) return;
    if (v == nv) { rowStart[nv] = ne; return; }
    int rs = rowStart[v] + partials[v / SCAN_TILE];
    rowStart[v] = rs;
    cursor[v] = rs;
    int d = deg[v];
    invdeg[v] = 1.0f / (float)(d > 1 ? d : 1);
}

// Init per-bucket append cursors: bucketCursor[b] = rowStart[min(b*512, nv)]
__global__ __launch_bounds__(256) void k_binit(const int* __restrict__ rowStart,
                                               int* __restrict__ bucketCursor, int nv) {
    int t = threadIdx.x;
    bucketCursor[t] = rowStart[min(t << 9, nv)];
}

// Bucketing pass: group (dst,src) pairs by dst>>9 into per-bucket global
// regions with dense (coalesced-run) writes. LDS-staged local grouping.
__global__ __launch_bounds__(256) void k_bucket(const int* __restrict__ esrc,
                                                const int* __restrict__ edst,
                                                int* __restrict__ bucketCursor,
                                                uint2* __restrict__ pairs, int ne) {
    __shared__ unsigned int hist[256];
    __shared__ unsigned int pref[256];
    __shared__ unsigned int curs[256];
    __shared__ unsigned int gbase[256];
    __shared__ uint2 stage[EPB];
    const int tid = threadIdx.x;
    const int base = blockIdx.x * EPB;
    const int n = min(EPB, ne - base);
    hist[tid] = 0;
    __syncthreads();
    for (int i = tid; i < n; i += 256)
        atomicAdd(&hist[((unsigned)edst[base + i]) >> 9], 1u);
    __syncthreads();
    const unsigned int h = hist[tid];
    pref[tid] = h;
    __syncthreads();
    #pragma unroll
    for (int off = 1; off < 256; off <<= 1) {
        unsigned int t = (tid >= off) ? pref[tid - off] : 0;
        __syncthreads();
        pref[tid] += t;
        __syncthreads();
    }
    const unsigned int excl = pref[tid] - h;
    gbase[tid] = h ? (unsigned int)atomicAdd(&bucketCursor[tid], (int)h) : 0u;
    __syncthreads();          // everyone done reading pref as inclusive scan
    pref[tid] = excl;
    curs[tid] = excl;
    __syncthreads();
    for (int i = tid; i < n; i += 256) {
        int d = edst[base + i];
        int s = esrc[base + i];
        unsigned int p = atomicAdd(&curs[((unsigned)d) >> 9], 1u);
        stage[p] = make_uint2((unsigned)d, (unsigned)s);
    }
    __syncthreads();
    for (int i = tid; i < n; i += 256) {
        uint2 pr = stage[i];
        unsigned int b = pr.x >> 9;
        pairs[gbase[b] + (unsigned)i - pref[b]] = pr;
    }
}

// Within-bucket scatter: one block per bucket; LDS cursors + LDS out buffer,
// all global reads/writes coalesced.
__global__ __launch_bounds__(256) void k_binsort(const uint2* __restrict__ pairs,
                                                 const int* __restrict__ rowStart,
                                                 int* __restrict__ cursorGlobal,
                                                 int* __restrict__ csrSrc, int nv) {
    __shared__ int cur[512];
    __shared__ int outbuf[BIN_CAP];
    const int tid = threadIdx.x;
    const int b = blockIdx.x;
    const int vbase = b << 9;
    if (vbase >= nv) return;
    const int vend = min(vbase + 512, nv);
    const int gs = rowStart[vbase];
    const int ge = rowStart[vend];
    const int count = ge - gs;
    for (int v = vbase + tid; v < vend; v += 256) cur[v - vbase] = rowStart[v] - gs;
    __syncthreads();
    if (count <= BIN_CAP) {
        for (int i = tid; i < count; i += 256) {
            uint2 p = pairs[gs + i];
            int pos = atomicAdd(&cur[p.x - (unsigned)vbase], 1);
            outbuf[pos] = (int)p.y;
        }
        __syncthreads();
        for (int i = tid; i < count; i += 256) csrSrc[gs + i] = outbuf[i];
    } else {
        // statistically unreachable fallback (correctness-preserving)
        for (int i = tid; i < count; i += 256) {
            uint2 p = pairs[gs + i];
            int pos = atomicAdd(&cursorGlobal[p.x], 1);
            csrSrc[pos] = (int)p.y;
        }
    }
}

// ---------------------------------------------------------------------------
// Image transpose: img[16][128][128][128] fp32 -> timg[x][y][z][16] bf16.
// 4 channels per thread (4 independent float4 loads, all in flight before one
// vmcnt wait; low VGPR -> 8 waves/SIMD; 32768 waves for latency hiding).
__global__ __launch_bounds__(256) void k_transpose(const float* __restrict__ img,
                                                   unsigned int* __restrict__ timg) {
    const int t = blockIdx.x * 256 + threadIdx.x;   // 128*128*32*4 threads
    const int q  = t & 3;            // channel quad -> channels 4q..4q+3
    const int z4 = (t >> 2) & 31;    // z block of 4
    const int xy = t >> 7;
    const int z0 = z4 * 4;
    const int c0 = q * 4;
    const size_t base = (size_t)xy * GRIDSZ + z0;
    float4 v0 = *(const float4*)(img + (size_t)(c0 + 0) * VOL + base);
    float4 v1 = *(const float4*)(img + (size_t)(c0 + 1) * VOL + base);
    float4 v2 = *(const float4*)(img + (size_t)(c0 + 2) * VOL + base);
    float4 v3 = *(const float4*)(img + (size_t)(c0 + 3) * VOL + base);
    #pragma unroll
    for (int j = 0; j < 4; ++j) {
        float f0 = (j == 0) ? v0.x : (j == 1) ? v0.y : (j == 2) ? v0.z : v0.w;
        float f1 = (j == 0) ? v1.x : (j == 1) ? v1.y : (j == 2) ? v1.z : v1.w;
        float f2 = (j == 0) ? v2.x : (j == 1) ? v2.y : (j == 2) ? v2.z : v2.w;
        float f3 = (j == 0) ? v3.x : (j == 1) ? v3.y : (j == 2) ? v3.z : v3.w;
        uint2 o;
        o.x = bf16_pack2(f0, f1);
        o.y = bf16_pack2(f2, f3);
        *(uint2*)(timg + (size_t)(xy * GRIDSZ + z0 + j) * 8 + q * 2) = o;
    }
}

// ---------------------------------------------------------------------------
// Trilinear sample from channel-last bf16 volume. 2 threads per vertex.
// feats cols: 0..15 = channels, 16..18 = verts/128, 19 = pad(0).
__global__ __launch_bounds__(256) void k_sample(const unsigned int* __restrict__ timg,
                                                const float* __restrict__ verts,
                                                float* __restrict__ feats, int nv) {
    int t = blockIdx.x * 256 + threadIdx.x;
    int v = t >> 1;
    int q = t & 1;          // channel group: q*8 .. q*8+7
    if (v >= nv) return;
    float px = verts[v * 3 + 0];
    float py = verts[v * 3 + 1];
    float pz = verts[v * 3 + 2];
    float cx = fminf(fmaxf(px, 0.0f), 127.0f);
    float cy = fminf(fmaxf(py, 0.0f), 127.0f);
    float cz = fminf(fmaxf(pz, 0.0f), 127.0f);
    float fx = floorf(cx), fy = floorf(cy), fz = floorf(cz);
    int x0 = (int)fx, y0 = (int)fy, z0 = (int)fz;
    int x1 = min(x0 + 1, 127), y1 = min(y0 + 1, 127), z1 = min(z0 + 1, 127);
    float wx = cx - fx, wy = cy - fy, wz = cz - fz;
    const int qo = q * 4;   // uint offset within 8-uint row
    #define LD(X, Y, Z) (*(const uint4*)(timg + ((size_t)((((X) << 7) + (Y)) << 7) + (size_t)(Z)) * 8 + qo))
    uint4 f000 = LD(x0, y0, z0), f001 = LD(x0, y0, z1);
    uint4 f010 = LD(x0, y1, z0), f011 = LD(x0, y1, z1);
    uint4 f100 = LD(x1, y0, z0), f101 = LD(x1, y0, z1);
    uint4 f110 = LD(x1, y1, z0), f111 = LD(x1, y1, z1);
    #undef LD
    float r[8];
    const unsigned int* a000 = (const unsigned int*)&f000;
    const unsigned int* a001 = (const unsigned int*)&f001;
    const unsigned int* a010 = (const unsigned int*)&f010;
    const unsigned int* a011 = (const unsigned int*)&f011;
    const unsigned int* a100 = (const unsigned int*)&f100;
    const unsigned int* a101 = (const unsigned int*)&f101;
    const unsigned int* a110 = (const unsigned int*)&f110;
    const unsigned int* a111 = (const unsigned int*)&f111;
    #pragma unroll
    for (int u = 0; u < 4; ++u) {
        float c00l = bf_lo(a000[u]) * (1.f - wz) + bf_lo(a001[u]) * wz;
        float c01l = bf_lo(a010[u]) * (1.f - wz) + bf_lo(a011[u]) * wz;
        float c10l = bf_lo(a100[u]) * (1.f - wz) + bf_lo(a101[u]) * wz;
        float c11l = bf_lo(a110[u]) * (1.f - wz) + bf_lo(a111[u]) * wz;
        r[2 * u] = (c00l * (1.f - wy) + c01l * wy) * (1.f - wx) +
                   (c10l * (1.f - wy) + c11l * wy) * wx;
        float c00h = bf_hi(a000[u]) * (1.f - wz) + bf_hi(a001[u]) * wz;
        float c01h = bf_hi(a010[u]) * (1.f - wz) + bf_hi(a011[u]) * wz;
        float c10h = bf_hi(a100[u]) * (1.f - wz) + bf_hi(a101[u]) * wz;
        float c11h = bf_hi(a110[u]) * (1.f - wz) + bf_hi(a111[u]) * wz;
        r[2 * u + 1] = (c00h * (1.f - wy) + c01h * wy) * (1.f - wx) +
                       (c10h * (1.f - wy) + c11h * wy) * wx;
    }
    float* row = feats + (size_t)v * 20 + q * 8;
    *(float4*)(row + 0) = make_float4(r[0], r[1], r[2], r[3]);
    *(float4*)(row + 4) = make_float4(r[4], r[5], r[6], r[7]);
    if (q == 0) {
        *(float4*)(feats + (size_t)v * 20 + 16) =
            make_float4(px * (1.0f / 128.0f), py * (1.0f / 128.0f), pz * (1.0f / 128.0f), 0.0f);
    }
}

// ---------------------------------------------------------------------------
// CSR gather-sum
template <int S>
__global__ __launch_bounds__(256) void k_gather(const float* __restrict__ x,
                                                const int* __restrict__ rowStart,
                                                const int* __restrict__ csrSrc,
                                                float* __restrict__ nb, int nv) {
    constexpr int NCH = S / 4;
    int t = blockIdx.x * 256 + threadIdx.x;
    int v = t / NCH;
    if (v >= nv) return;
    int ch = t - v * NCH;
    int beg = rowStart[v];
    int end = rowStart[v + 1];
    float4 acc = make_float4(0.f, 0.f, 0.f, 0.f);
    for (int j = beg; j < end; ++j) {
        int s = csrSrc[j];
        float4 q = ((const float4*)(x + (size_t)s * S))[ch];
        acc.x += q.x; acc.y += q.y; acc.z += q.z; acc.w += q.w;
    }
    ((float4*)(nb + (size_t)v * S))[ch] = acc;
}

// ---------------------------------------------------------------------------
// Edge-conv dense part. REMAP0: feats cols are [ch16, verts3, pad]; weight
// rows in reference order are [verts3, ch16] -> srcrow = k<16 ? k+3 : k-16.
template <int CIN, int COUT, int SX, bool RELU, bool REMAP0>
__global__ __launch_bounds__(256) void k_layer(const float* __restrict__ x,
                                               const float* __restrict__ nb,
                                               const float* __restrict__ invdeg,
                                               const float* __restrict__ Ws,
                                               const float* __restrict__ Wn,
                                               const float* __restrict__ b,
                                               float* __restrict__ out, int nv) {
    constexpr int GR = COUT / 8;              // co-groups of 8 per vertex
    constexpr int VPT = 4;                    // vertices per thread
    constexpr int TPB = 256;
    constexpr int VPB = (TPB / GR) * VPT;     // vertices per block
    constexpr int KP = (CIN + 3) & ~3;        // K padded to multiple of 4
    __shared__ float ws_s[KP * COUT];
    __shared__ float wn_s[KP * COUT];
    for (int i = threadIdx.x; i < KP * COUT; i += TPB) {
        int k = i / COUT, c = i - k * COUT;
        float vs = 0.f, vn = 0.f;
        if (k < CIN) {
            int sr = REMAP0 ? ((k < 16) ? (k + 3) : (k - 16)) : k;
            vs = Ws[sr * COUT + c];
            vn = Wn[sr * COUT + c];
        }
        ws_s[i] = vs;
        wn_s[i] = vn;
    }
    __syncthreads();

    const int g = threadIdx.x % GR;
    const int co = g * 8;
    const int vt = threadIdx.x / GR;
    const int v0 = blockIdx.x * VPB + vt * VPT;

    float acc_s[VPT][8], acc_n[VPT][8];
    #pragma unroll
    for (int u = 0; u < VPT; ++u)
        #pragma unroll
        for (int i = 0; i < 8; ++i) { acc_s[u][i] = 0.f; acc_n[u][i] = 0.f; }

    for (int k = 0; k < KP; k += 4) {
        float4 xq[VPT], nq[VPT];
        #pragma unroll
        for (int u = 0; u < VPT; ++u) {
            int v = v0 + u;
            if (v < nv) {
                xq[u] = *(const float4*)(x + (size_t)v * SX + k);
                nq[u] = *(const float4*)(nb + (size_t)v * SX + k);
            } else {
                xq[u] = make_float4(0.f, 0.f, 0.f, 0.f);
                nq[u] = make_float4(0.f, 0.f, 0.f, 0.f);
            }
        }
        #pragma unroll
        for (int j = 0; j < 4; ++j) {
            const float4 wsa = *(const float4*)(ws_s + (k + j) * COUT + co);
            const float4 wsb = *(const float4*)(ws_s + (k + j) * COUT + co + 4);
            const float4 wna = *(const float4*)(wn_s + (k + j) * COUT + co);
            const float4 wnb = *(const float4*)(wn_s + (k + j) * COUT + co + 4);
            #pragma unroll
            for (int u = 0; u < VPT; ++u) {
                float xv = (j == 0) ? xq[u].x : (j == 1) ? xq[u].y : (j == 2) ? xq[u].z : xq[u].w;
                float nw = (j == 0) ? nq[u].x : (j == 1) ? nq[u].y : (j == 2) ? nq[u].z : nq[u].w;
                acc_s[u][0] += xv * wsa.x; acc_s[u][1] += xv * wsa.y;
                acc_s[u][2] += xv * wsa.z; acc_s[u][3] += xv * wsa.w;
                acc_s[u][4] += xv * wsb.x; acc_s[u][5] += xv * wsb.y;
                acc_s[u][6] += xv * wsb.z; acc_s[u][7] += xv * wsb.w;
                acc_n[u][0] += nw * wna.x; acc_n[u][1] += nw * wna.y;
                acc_n[u][2] += nw * wna.z; acc_n[u][3] += nw * wna.w;
                acc_n[u][4] += nw * wnb.x; acc_n[u][5] += nw * wnb.y;
                acc_n[u][6] += nw * wnb.z; acc_n[u][7] += nw * wnb.w;
            }
        }
    }

    #pragma unroll
    for (int u = 0; u < VPT; ++u) {
        int v = v0 + u;
        if (v >= nv) continue;
        float id = invdeg[v];
        float r[8];
        #pragma unroll
        for (int i = 0; i < 8; ++i) {
            float t = acc_s[u][i] + acc_n[u][i] * id + b[co + i];
            r[i] = (!RELU || t >= 0.f) ? t : SLOPE * t;
        }
        float4* op = (float4*)(out + (size_t)v * COUT + co);
        op[0] = make_float4(r[0], r[1], r[2], r[3]);
        op[1] = make_float4(r[4], r[5], r[6], r[7]);
    }
}

// Pre-multiply for layer 3: z[v][j] = h3[v] @ Wn3 (j<3), z stride 4, pad 0.
__global__ __launch_bounds__(256) void k_premul(const float* __restrict__ h,
                                                const float* __restrict__ wn,
                                                float* __restrict__ z, int nv) {
    __shared__ float w_s[64 * 3];
    if (threadIdx.x < 64 * 3) w_s[threadIdx.x] = wn[threadIdx.x];
    __syncthreads();
    int v = blockIdx.x * 256 + threadIdx.x;
    if (v >= nv) return;
    const float4* hr = (const float4*)(h + (size_t)v * 64);
    float a0 = 0.f, a1 = 0.f, a2 = 0.f;
    #pragma unroll
    for (int q = 0; q < 16; ++q) {
        float4 hv = hr[q];
        int k = q * 4;
        a0 += hv.x * w_s[k * 3 + 0] + hv.y * w_s[k * 3 + 3] + hv.z * w_s[k * 3 + 6] + hv.w * w_s[k * 3 + 9];
        a1 += hv.x * w_s[k * 3 + 1] + hv.y * w_s[k * 3 + 4] + hv.z * w_s[k * 3 + 7] + hv.w * w_s[k * 3 + 10];
        a2 += hv.x * w_s[k * 3 + 2] + hv.y * w_s[k * 3 + 5] + hv.z * w_s[k * 3 + 8] + hv.w * w_s[k * 3 + 11];
    }
    *((float4*)(z + (size_t)v * 4)) = make_float4(a0, a1, a2, 0.f);
}

// Final: out = verts + SCALE*(h3@Ws3 + nb3*inv_deg + b3)
__global__ __launch_bounds__(256) void k_final(const float* __restrict__ h,
                                               const float* __restrict__ nb,
                                               const float* __restrict__ invdeg,
                                               const float* __restrict__ ws,
                                               const float* __restrict__ b,
                                               const float* __restrict__ verts,
                                               float* __restrict__ out, int nv) {
    __shared__ float w_s[64 * 3];
    if (threadIdx.x < 64 * 3) w_s[threadIdx.x] = ws[threadIdx.x];
    __syncthreads();
    int v = blockIdx.x * 256 + threadIdx.x;
    if (v >= nv) return;
    const float4* hr = (const float4*)(h + (size_t)v * 64);
    float a0 = b[0], a1 = b[1], a2 = b[2];
    #pragma unroll
    for (int q = 0; q < 16; ++q) {
        float4 hv = hr[q];
        int k = q * 4;
        a0 += hv.x * w_s[k * 3 + 0] + hv.y * w_s[k * 3 + 3] + hv.z * w_s[k * 3 + 6] + hv.w * w_s[k * 3 + 9];
        a1 += hv.x * w_s[k * 3 + 1] + hv.y * w_s[k * 3 + 4] + hv.z * w_s[k * 3 + 7] + hv.w * w_s[k * 3 + 10];
        a2 += hv.x * w_s[k * 3 + 2] + hv.y * w_s[k * 3 + 5] + hv.z * w_s[k * 3 + 8] + hv.w * w_s[k * 3 + 11];
    }
    float id = invdeg[v];
    float4 nq = *((const float4*)(nb + (size_t)v * 4));
    a0 += nq.x * id; a1 += nq.y * id; a2 += nq.z * id;
    out[(size_t)v * 3 + 0] = verts[(size_t)v * 3 + 0] + SCALE * a0;
    out[(size_t)v * 3 + 1] = verts[(size_t)v * 3 + 1] + SCALE * a1;
    out[(size_t)v * 3 + 2] = verts[(size_t)v * 3 + 2] + SCALE * a2;
}

// ---------------------------------------------------------------------------
extern "C" void kernel_launch(void* const* d_in, const int* in_sizes, int n_in,
                              void* d_out, int out_size, void* d_ws, size_t ws_size,
                              hipStream_t stream) {
    const float* img   = (const float*)d_in[0];
    const float* verts = (const float*)d_in[1];
    const int*   esrc  = (const int*)d_in[2];
    const int*   edst  = (const int*)d_in[3];
    const float* ws0 = (const float*)d_in[4];
    const float* wn0 = (const float*)d_in[5];
    const float* b0  = (const float*)d_in[6];
    const float* ws1 = (const float*)d_in[7];
    const float* wn1 = (const float*)d_in[8];
    const float* b1  = (const float*)d_in[9];
    const float* ws2 = (const float*)d_in[10];
    const float* wn2 = (const float*)d_in[11];
    const float* b2  = (const float*)d_in[12];
    const float* ws3 = (const float*)d_in[13];
    const float* wn3 = (const float*)d_in[14];
    const float* b3  = (const float*)d_in[15];

    const int nv = in_sizes[1] / 3;
    const int ne = in_sizes[2];

    char* base = (char*)d_ws;
    size_t off = 0;
    auto alloc = [&](size_t bytes) -> void* {
        off = (off + 255) & ~(size_t)255;
        void* p = base + off;
        off += bytes;
        return p;
    };
    int*   deg      = (int*)alloc((size_t)nv * 4);
    float* invdeg   = (float*)alloc((size_t)nv * 4);
    int*   rowStart = (int*)alloc((size_t)(nv + 1) * 4);
    int*   cursor   = (int*)alloc((size_t)nv * 4);
    int*   partials = (int*)alloc(256 * 4);
    int*   bucketCursor = (int*)alloc(256 * 4);
    int*   csrSrc   = (int*)alloc((size_t)ne * 4);
    float* A        = (float*)alloc((size_t)nv * 64 * 4);  // feats(20) then h2(64)
    float* B        = (float*)alloc((size_t)nv * 64 * 4);  // h1(32) then h3(64)
    float* NB       = (float*)alloc((size_t)nv * 64 * 4);  // neighbor sums
    float* Z        = (float*)alloc((size_t)nv * 4 * 4);   // premultiplied layer-3
    unsigned int* timg = (unsigned int*)alloc((size_t)VOL * 16 * 2); // bf16 channel-last
    uint2* pairs = (uint2*)NB;   // alias: NB unused until gathers (needs ne*8 <= nv*256 B)

    auto blocks = [](long long n) { return (int)((n + 255) / 256); };
    const int np = (nv + SCAN_TILE - 1) / SCAN_TILE;
    const int nbuckets = (nv + 511) >> 9;

    // Image transpose (independent of CSR build)
    k_transpose<<<(GRIDSZ * GRIDSZ * 32 * 4) / 256, 256, 0, stream>>>(img, timg);

    // CSR build: degree -> scan -> bucketed counting sort
    hipMemsetAsync(deg, 0, (size_t)nv * 4, stream);
    k_deg<<<blocks(ne), 256, 0, stream>>>(edst, deg, ne);
    k_scan1<<<np, 256, 0, stream>>>(deg, rowStart, partials, nv);
    k_scan2<<<1, 256, 0, stream>>>(partials, np);
    k_vinit<<<blocks(nv + 1), 256, 0, stream>>>(deg, rowStart, partials, invdeg, cursor, nv, ne);
    k_binit<<<1, 256, 0, stream>>>(rowStart, bucketCursor, nv);
    k_bucket<<<(ne + EPB - 1) / EPB, 256, 0, stream>>>(esrc, edst, bucketCursor, pairs, ne);
    k_binsort<<<nbuckets, 256, 0, stream>>>(pairs, rowStart, cursor, csrSrc, nv);

    // Features (channel-last bf16 volume)
    k_sample<<<blocks((long long)nv * 2), 256, 0, stream>>>(timg, verts, A, nv);

    // Layer 0: 19 -> 32 (weight rows remapped for reordered feats)
    k_gather<20><<<blocks((long long)nv * 5), 256, 0, stream>>>(A, rowStart, csrSrc, NB, nv);
    k_layer<19, 32, 20, true, true><<<(nv + 255) / 256, 256, 0, stream>>>(
        A, NB, invdeg, ws0, wn0, b0, B, nv);

    // Layer 1: 32 -> 64
    k_gather<32><<<blocks((long long)nv * 8), 256, 0, stream>>>(B, rowStart, csrSrc, NB, nv);
    k_layer<32, 64, 32, true, false><<<(nv + 127) / 128, 256, 0, stream>>>(
        B, NB, invdeg, ws1, wn1, b1, A, nv);

    // Layer 2: 64 -> 64
    k_gather<64><<<blocks((long long)nv * 16), 256, 0, stream>>>(A, rowStart, csrSrc, NB, nv);
    k_layer<64, 64, 64, true, false><<<(nv + 127) / 128, 256, 0, stream>>>(
        A, NB, invdeg, ws2, wn2, b2, B, nv);

    // Layer 3: pre-multiply by Wn3 (64->3), gather 4 floats, fuse final update
    k_premul<<<blocks(nv), 256, 0, stream>>>(B, wn3, Z, nv);
    k_gather<4><<<blocks(nv), 256, 0, stream>>>(Z, rowStart, csrSrc, NB, nv);
    k_final<<<blocks(nv), 256, 0, stream>>>(
        B, NB, invdeg, ws3, b3, verts, (float*)d_out, nv);
}

// Round 7
// 564.478 us; speedup vs baseline: 2.0439x; 1.1376x over previous
//
#include <hip/hip_runtime.h>

// Problem constants (from reference)
#define C_IMG 16
#define GRIDSZ 128
#define VOL (GRIDSZ * GRIDSZ * GRIDSZ)
#define SLOPE 0.3f
#define SCALE 0.1f
#define SCAN_TILE 1024   // elements per scan-pass-1 block (256 thr x 4)
#define EPB 4096         // edges per k_bucket block
#define BIN_CAP 16384    // max edges per 512-vertex bucket (mean 8192, sd ~90)

// bf16 helpers (manual, RNE pack / shift unpack)
__device__ __forceinline__ unsigned int bf16_pack2(float a, float b) {
    unsigned int ua = __float_as_uint(a);
    ua = (ua + 0x7FFFu + ((ua >> 16) & 1u)) >> 16;
    unsigned int ub = __float_as_uint(b);
    ub = (ub + 0x7FFFu + ((ub >> 16) & 1u)) >> 16;
    return ua | (ub << 16);
}
__device__ __forceinline__ float bf_lo(unsigned int u) { return __uint_as_float(u << 16); }
__device__ __forceinline__ float bf_hi(unsigned int u) { return __uint_as_float(u & 0xFFFF0000u); }

// ---------------------------------------------------------------------------
// Degree count (int atomics)
__global__ __launch_bounds__(256) void k_deg(const int* __restrict__ edst,
                                             int* __restrict__ deg, int ne) {
    int e = blockIdx.x * 256 + threadIdx.x;
    if (e >= ne) return;
    atomicAdd(&deg[edst[e]], 1);
}

// Multi-block scan pass 1
__global__ __launch_bounds__(256) void k_scan1(const int* __restrict__ deg,
                                               int* __restrict__ rowStart,
                                               int* __restrict__ partials, int nv) {
    __shared__ int ssum[256];
    const int tid = threadIdx.x;
    const int idx = blockIdx.x * SCAN_TILE + tid * 4;
    int d0 = 0, d1 = 0, d2 = 0, d3 = 0;
    if (idx + 3 < nv) {
        int4 q = *(const int4*)(deg + idx);
        d0 = q.x; d1 = q.y; d2 = q.z; d3 = q.w;
    } else {
        if (idx + 0 < nv) d0 = deg[idx + 0];
        if (idx + 1 < nv) d1 = deg[idx + 1];
        if (idx + 2 < nv) d2 = deg[idx + 2];
        if (idx + 3 < nv) d3 = deg[idx + 3];
    }
    const int tsum = d0 + d1 + d2 + d3;
    ssum[tid] = tsum;
    __syncthreads();
    #pragma unroll
    for (int off = 1; off < 256; off <<= 1) {
        int t = (tid >= off) ? ssum[tid - off] : 0;
        __syncthreads();
        ssum[tid] += t;
        __syncthreads();
    }
    const int excl = ssum[tid] - tsum;
    if (tid == 255) partials[blockIdx.x] = ssum[255];
    if (idx + 0 < nv) rowStart[idx + 0] = excl;
    if (idx + 1 < nv) rowStart[idx + 1] = excl + d0;
    if (idx + 2 < nv) rowStart[idx + 2] = excl + d0 + d1;
    if (idx + 3 < nv) rowStart[idx + 3] = excl + d0 + d1 + d2;
}

// Pass 2: exclusive scan of tile totals in place (np <= 256).
__global__ __launch_bounds__(256) void k_scan2(int* __restrict__ partials, int np) {
    __shared__ int buf[256];
    const int tid = threadIdx.x;
    const int v = (tid < np) ? partials[tid] : 0;
    buf[tid] = v;
    __syncthreads();
    #pragma unroll
    for (int off = 1; off < 256; off <<= 1) {
        int t = (tid >= off) ? buf[tid - off] : 0;
        __syncthreads();
        buf[tid] += t;
        __syncthreads();
    }
    if (tid < np) partials[tid] = buf[tid] - v;
}

// Pass 3 + vertex init + bucket cursor init (b*512 < nv for all used buckets)
__global__ __launch_bounds__(256) void k_vinit(const int* __restrict__ deg,
                                               int* __restrict__ rowStart,
                                               const int* __restrict__ partials,
                                               float* __restrict__ invdeg,
                                               int* __restrict__ cursor,
                                               int* __restrict__ bucketCursor,
                                               int nv, int ne) {
    int v = blockIdx.x * 256 + threadIdx.x;
    if (v > nv) return;
    if (v == nv) { rowStart[nv] = ne; return; }
    int rs = rowStart[v] + partials[v / SCAN_TILE];
    rowStart[v] = rs;
    cursor[v] = rs;
    if ((v & 511) == 0) bucketCursor[v >> 9] = rs;
    int d = deg[v];
    invdeg[v] = 1.0f / (float)(d > 1 ? d : 1);
}

// Bucketing pass: group (dst,src) pairs by dst>>9 into per-bucket global
// regions with dense (coalesced-run) writes. LDS-staged local grouping.
__global__ __launch_bounds__(256) void k_bucket(const int* __restrict__ esrc,
                                                const int* __restrict__ edst,
                                                int* __restrict__ bucketCursor,
                                                uint2* __restrict__ pairs, int ne) {
    __shared__ unsigned int hist[256];
    __shared__ unsigned int pref[256];
    __shared__ unsigned int curs[256];
    __shared__ unsigned int gbase[256];
    __shared__ uint2 stage[EPB];
    const int tid = threadIdx.x;
    const int base = blockIdx.x * EPB;
    const int n = min(EPB, ne - base);
    hist[tid] = 0;
    __syncthreads();
    for (int i = tid; i < n; i += 256)
        atomicAdd(&hist[((unsigned)edst[base + i]) >> 9], 1u);
    __syncthreads();
    const unsigned int h = hist[tid];
    pref[tid] = h;
    __syncthreads();
    #pragma unroll
    for (int off = 1; off < 256; off <<= 1) {
        unsigned int t = (tid >= off) ? pref[tid - off] : 0;
        __syncthreads();
        pref[tid] += t;
        __syncthreads();
    }
    const unsigned int excl = pref[tid] - h;
    gbase[tid] = h ? (unsigned int)atomicAdd(&bucketCursor[tid], (int)h) : 0u;
    __syncthreads();
    pref[tid] = excl;
    curs[tid] = excl;
    __syncthreads();
    for (int i = tid; i < n; i += 256) {
        int d = edst[base + i];
        int s = esrc[base + i];
        unsigned int p = atomicAdd(&curs[((unsigned)d) >> 9], 1u);
        stage[p] = make_uint2((unsigned)d, (unsigned)s);
    }
    __syncthreads();
    for (int i = tid; i < n; i += 256) {
        uint2 pr = stage[i];
        unsigned int b = pr.x >> 9;
        pairs[gbase[b] + (unsigned)i - pref[b]] = pr;
    }
}

// Within-bucket scatter: one block per bucket; LDS cursors + LDS out buffer.
__global__ __launch_bounds__(256) void k_binsort(const uint2* __restrict__ pairs,
                                                 const int* __restrict__ rowStart,
                                                 int* __restrict__ cursorGlobal,
                                                 int* __restrict__ csrSrc, int nv) {
    __shared__ int cur[512];
    __shared__ int outbuf[BIN_CAP];
    const int tid = threadIdx.x;
    const int b = blockIdx.x;
    const int vbase = b << 9;
    if (vbase >= nv) return;
    const int vend = min(vbase + 512, nv);
    const int gs = rowStart[vbase];
    const int ge = rowStart[vend];
    const int count = ge - gs;
    for (int v = vbase + tid; v < vend; v += 256) cur[v - vbase] = rowStart[v] - gs;
    __syncthreads();
    if (count <= BIN_CAP) {
        for (int i = tid; i < count; i += 256) {
            uint2 p = pairs[gs + i];
            int pos = atomicAdd(&cur[p.x - (unsigned)vbase], 1);
            outbuf[pos] = (int)p.y;
        }
        __syncthreads();
        for (int i = tid; i < count; i += 256) csrSrc[gs + i] = outbuf[i];
    } else {
        for (int i = tid; i < count; i += 256) {
            uint2 p = pairs[gs + i];
            int pos = atomicAdd(&cursorGlobal[p.x], 1);
            csrSrc[pos] = (int)p.y;
        }
    }
}

// ---------------------------------------------------------------------------
// Image transpose: img[16][128][128][128] fp32 -> timg[x][y][z][16] bf16.
// 4 channels per thread (4 independent float4 loads before one vmcnt wait).
__global__ __launch_bounds__(256) void k_transpose(const float* __restrict__ img,
                                                   unsigned int* __restrict__ timg) {
    const int t = blockIdx.x * 256 + threadIdx.x;
    const int q  = t & 3;
    const int z4 = (t >> 2) & 31;
    const int xy = t >> 7;
    const int z0 = z4 * 4;
    const int c0 = q * 4;
    const size_t base = (size_t)xy * GRIDSZ + z0;
    float4 v0 = *(const float4*)(img + (size_t)(c0 + 0) * VOL + base);
    float4 v1 = *(const float4*)(img + (size_t)(c0 + 1) * VOL + base);
    float4 v2 = *(const float4*)(img + (size_t)(c0 + 2) * VOL + base);
    float4 v3 = *(const float4*)(img + (size_t)(c0 + 3) * VOL + base);
    #pragma unroll
    for (int j = 0; j < 4; ++j) {
        float f0 = (j == 0) ? v0.x : (j == 1) ? v0.y : (j == 2) ? v0.z : v0.w;
        float f1 = (j == 0) ? v1.x : (j == 1) ? v1.y : (j == 2) ? v1.z : v1.w;
        float f2 = (j == 0) ? v2.x : (j == 1) ? v2.y : (j == 2) ? v2.z : v2.w;
        float f3 = (j == 0) ? v3.x : (j == 1) ? v3.y : (j == 2) ? v3.z : v3.w;
        uint2 o;
        o.x = bf16_pack2(f0, f1);
        o.y = bf16_pack2(f2, f3);
        *(uint2*)(timg + (size_t)(xy * GRIDSZ + z0 + j) * 8 + q * 2) = o;
    }
}

// ---------------------------------------------------------------------------
// Trilinear sample -> bf16 feats rows, stride 16 uints (32 bf16 cols):
// cols 0..15 = channels, 16..18 = verts/128, 19..31 = 0.
__global__ __launch_bounds__(256) void k_sample(const unsigned int* __restrict__ timg,
                                                const float* __restrict__ verts,
                                                unsigned int* __restrict__ feats, int nv) {
    int t = blockIdx.x * 256 + threadIdx.x;
    int v = t >> 1;
    int q = t & 1;          // channel group: q*8 .. q*8+7
    if (v >= nv) return;
    float px = verts[v * 3 + 0];
    float py = verts[v * 3 + 1];
    float pz = verts[v * 3 + 2];
    float cx = fminf(fmaxf(px, 0.0f), 127.0f);
    float cy = fminf(fmaxf(py, 0.0f), 127.0f);
    float cz = fminf(fmaxf(pz, 0.0f), 127.0f);
    float fx = floorf(cx), fy = floorf(cy), fz = floorf(cz);
    int x0 = (int)fx, y0 = (int)fy, z0 = (int)fz;
    int x1 = min(x0 + 1, 127), y1 = min(y0 + 1, 127), z1 = min(z0 + 1, 127);
    float wx = cx - fx, wy = cy - fy, wz = cz - fz;
    const int qo = q * 4;
    #define LD(X, Y, Z) (*(const uint4*)(timg + ((size_t)((((X) << 7) + (Y)) << 7) + (size_t)(Z)) * 8 + qo))
    uint4 f000 = LD(x0, y0, z0), f001 = LD(x0, y0, z1);
    uint4 f010 = LD(x0, y1, z0), f011 = LD(x0, y1, z1);
    uint4 f100 = LD(x1, y0, z0), f101 = LD(x1, y0, z1);
    uint4 f110 = LD(x1, y1, z0), f111 = LD(x1, y1, z1);
    #undef LD
    float r[8];
    const unsigned int* a000 = (const unsigned int*)&f000;
    const unsigned int* a001 = (const unsigned int*)&f001;
    const unsigned int* a010 = (const unsigned int*)&f010;
    const unsigned int* a011 = (const unsigned int*)&f011;
    const unsigned int* a100 = (const unsigned int*)&f100;
    const unsigned int* a101 = (const unsigned int*)&f101;
    const unsigned int* a110 = (const unsigned int*)&f110;
    const unsigned int* a111 = (const unsigned int*)&f111;
    #pragma unroll
    for (int u = 0; u < 4; ++u) {
        float c00l = bf_lo(a000[u]) * (1.f - wz) + bf_lo(a001[u]) * wz;
        float c01l = bf_lo(a010[u]) * (1.f - wz) + bf_lo(a011[u]) * wz;
        float c10l = bf_lo(a100[u]) * (1.f - wz) + bf_lo(a101[u]) * wz;
        float c11l = bf_lo(a110[u]) * (1.f - wz) + bf_lo(a111[u]) * wz;
        r[2 * u] = (c00l * (1.f - wy) + c01l * wy) * (1.f - wx) +
                   (c10l * (1.f - wy) + c11l * wy) * wx;
        float c00h = bf_hi(a000[u]) * (1.f - wz) + bf_hi(a001[u]) * wz;
        float c01h = bf_hi(a010[u]) * (1.f - wz) + bf_hi(a011[u]) * wz;
        float c10h = bf_hi(a100[u]) * (1.f - wz) + bf_hi(a101[u]) * wz;
        float c11h = bf_hi(a110[u]) * (1.f - wz) + bf_hi(a111[u]) * wz;
        r[2 * u + 1] = (c00h * (1.f - wy) + c01h * wy) * (1.f - wx) +
                       (c10h * (1.f - wy) + c11h * wy) * wx;
    }
    unsigned int* row = feats + (size_t)v * 16;
    uint4 o;
    o.x = bf16_pack2(r[0], r[1]); o.y = bf16_pack2(r[2], r[3]);
    o.z = bf16_pack2(r[4], r[5]); o.w = bf16_pack2(r[6], r[7]);
    *(uint4*)(row + q * 4) = o;
    if (q == 0) {
        uint4 o2;
        o2.x = bf16_pack2(px * (1.0f / 128.0f), py * (1.0f / 128.0f));
        o2.y = bf16_pack2(pz * (1.0f / 128.0f), 0.0f);
        o2.z = 0u; o2.w = 0u;
        *(uint4*)(row + 8) = o2;
        *(uint4*)(row + 12) = make_uint4(0u, 0u, 0u, 0u);
    }
}

// ---------------------------------------------------------------------------
// CSR gather-sum over bf16 rows (stride SU uints). NCH=SU/4 threads per
// vertex, each owns a uint4 (8 ch) chunk; fp32 accumulate, bf16 output.
template <int SU>
__global__ __launch_bounds__(256) void k_gather16(const unsigned int* __restrict__ x,
                                                  const int* __restrict__ rowStart,
                                                  const int* __restrict__ csrSrc,
                                                  unsigned int* __restrict__ nb, int nv) {
    constexpr int NCH = SU / 4;
    int t = blockIdx.x * 256 + threadIdx.x;
    int v = t / NCH;
    if (v >= nv) return;
    int ch = t - v * NCH;
    int beg = rowStart[v];
    int end = rowStart[v + 1];
    float a0 = 0.f, a1 = 0.f, a2 = 0.f, a3 = 0.f, a4 = 0.f, a5 = 0.f, a6 = 0.f, a7 = 0.f;
    for (int j = beg; j < end; ++j) {
        int s = csrSrc[j];
        uint4 q = ((const uint4*)(x + (size_t)s * SU))[ch];
        a0 += bf_lo(q.x); a1 += bf_hi(q.x);
        a2 += bf_lo(q.y); a3 += bf_hi(q.y);
        a4 += bf_lo(q.z); a5 += bf_hi(q.z);
        a6 += bf_lo(q.w); a7 += bf_hi(q.w);
    }
    uint4 o;
    o.x = bf16_pack2(a0, a1); o.y = bf16_pack2(a2, a3);
    o.z = bf16_pack2(a4, a5); o.w = bf16_pack2(a6, a7);
    ((uint4*)(nb + (size_t)v * SU))[ch] = o;
}

// Small gather for premultiplied layer-3 rows (uint2 = 4 bf16); fp32 out.
__global__ __launch_bounds__(256) void k_gatherz(const unsigned int* __restrict__ z,
                                                 const int* __restrict__ rowStart,
                                                 const int* __restrict__ csrSrc,
                                                 float* __restrict__ nb, int nv) {
    int v = blockIdx.x * 256 + threadIdx.x;
    if (v >= nv) return;
    int beg = rowStart[v];
    int end = rowStart[v + 1];
    float a0 = 0.f, a1 = 0.f, a2 = 0.f;
    for (int j = beg; j < end; ++j) {
        int s = csrSrc[j];
        uint2 q = *(const uint2*)(z + (size_t)s * 2);
        a0 += bf_lo(q.x); a1 += bf_hi(q.x); a2 += bf_lo(q.y);
    }
    *(float4*)(nb + (size_t)v * 4) = make_float4(a0, a1, a2, 0.f);
}

// ---------------------------------------------------------------------------
// Edge-conv dense part over bf16 x/nb (stride SXU uints), bf16 out (COUT/2
// uints). Weights fp32 in LDS. REMAP0: srcrow = k<16 ? k+3 : k-16.
template <int CIN, int COUT, int SXU, bool RELU, bool REMAP0>
__global__ __launch_bounds__(256) void k_layer16(const unsigned int* __restrict__ x,
                                                 const unsigned int* __restrict__ nb,
                                                 const float* __restrict__ invdeg,
                                                 const float* __restrict__ Ws,
                                                 const float* __restrict__ Wn,
                                                 const float* __restrict__ b,
                                                 unsigned int* __restrict__ out, int nv) {
    constexpr int GR = COUT / 8;
    constexpr int VPT = 4;
    constexpr int TPB = 256;
    constexpr int VPB = (TPB / GR) * VPT;
    constexpr int KP = (CIN + 3) & ~3;
    constexpr int SOU = COUT / 2;
    __shared__ float ws_s[KP * COUT];
    __shared__ float wn_s[KP * COUT];
    for (int i = threadIdx.x; i < KP * COUT; i += TPB) {
        int k = i / COUT, c = i - k * COUT;
        float vs = 0.f, vn = 0.f;
        if (k < CIN) {
            int sr = REMAP0 ? ((k < 16) ? (k + 3) : (k - 16)) : k;
            vs = Ws[sr * COUT + c];
            vn = Wn[sr * COUT + c];
        }
        ws_s[i] = vs;
        wn_s[i] = vn;
    }
    __syncthreads();

    const int g = threadIdx.x % GR;
    const int co = g * 8;
    const int vt = threadIdx.x / GR;
    const int v0 = blockIdx.x * VPB + vt * VPT;

    float acc_s[VPT][8], acc_n[VPT][8];
    #pragma unroll
    for (int u = 0; u < VPT; ++u)
        #pragma unroll
        for (int i = 0; i < 8; ++i) { acc_s[u][i] = 0.f; acc_n[u][i] = 0.f; }

    for (int k = 0; k < KP; k += 4) {
        uint2 xq[VPT], nq[VPT];
        #pragma unroll
        for (int u = 0; u < VPT; ++u) {
            int v = v0 + u;
            if (v < nv) {
                xq[u] = *(const uint2*)(x + (size_t)v * SXU + (k >> 1));
                nq[u] = *(const uint2*)(nb + (size_t)v * SXU + (k >> 1));
            } else {
                xq[u] = make_uint2(0u, 0u);
                nq[u] = make_uint2(0u, 0u);
            }
        }
        #pragma unroll
        for (int j = 0; j < 4; ++j) {
            const float4 wsa = *(const float4*)(ws_s + (k + j) * COUT + co);
            const float4 wsb = *(const float4*)(ws_s + (k + j) * COUT + co + 4);
            const float4 wna = *(const float4*)(wn_s + (k + j) * COUT + co);
            const float4 wnb = *(const float4*)(wn_s + (k + j) * COUT + co + 4);
            #pragma unroll
            for (int u = 0; u < VPT; ++u) {
                float xv = (j == 0) ? bf_lo(xq[u].x) : (j == 1) ? bf_hi(xq[u].x)
                         : (j == 2) ? bf_lo(xq[u].y) : bf_hi(xq[u].y);
                float nw = (j == 0) ? bf_lo(nq[u].x) : (j == 1) ? bf_hi(nq[u].x)
                         : (j == 2) ? bf_lo(nq[u].y) : bf_hi(nq[u].y);
                acc_s[u][0] += xv * wsa.x; acc_s[u][1] += xv * wsa.y;
                acc_s[u][2] += xv * wsa.z; acc_s[u][3] += xv * wsa.w;
                acc_s[u][4] += xv * wsb.x; acc_s[u][5] += xv * wsb.y;
                acc_s[u][6] += xv * wsb.z; acc_s[u][7] += xv * wsb.w;
                acc_n[u][0] += nw * wna.x; acc_n[u][1] += nw * wna.y;
                acc_n[u][2] += nw * wna.z; acc_n[u][3] += nw * wna.w;
                acc_n[u][4] += nw * wnb.x; acc_n[u][5] += nw * wnb.y;
                acc_n[u][6] += nw * wnb.z; acc_n[u][7] += nw * wnb.w;
            }
        }
    }

    #pragma unroll
    for (int u = 0; u < VPT; ++u) {
        int v = v0 + u;
        if (v >= nv) continue;
        float id = invdeg[v];
        float r[8];
        #pragma unroll
        for (int i = 0; i < 8; ++i) {
            float t = acc_s[u][i] + acc_n[u][i] * id + b[co + i];
            r[i] = (!RELU || t >= 0.f) ? t : SLOPE * t;
        }
        uint4 o;
        o.x = bf16_pack2(r[0], r[1]); o.y = bf16_pack2(r[2], r[3]);
        o.z = bf16_pack2(r[4], r[5]); o.w = bf16_pack2(r[6], r[7]);
        *(uint4*)(out + (size_t)v * SOU + (co >> 1)) = o;
    }
}

// Pre-multiply for layer 3: z[v] = h3[v] @ Wn3 (3 cols), bf16 in/out.
__global__ __launch_bounds__(256) void k_premul(const unsigned int* __restrict__ h,
                                                const float* __restrict__ wn,
                                                unsigned int* __restrict__ z, int nv) {
    __shared__ float w_s[64 * 3];
    if (threadIdx.x < 64 * 3) w_s[threadIdx.x] = wn[threadIdx.x];
    __syncthreads();
    int v = blockIdx.x * 256 + threadIdx.x;
    if (v >= nv) return;
    const uint4* hr = (const uint4*)(h + (size_t)v * 32);
    float a0 = 0.f, a1 = 0.f, a2 = 0.f;
    #pragma unroll
    for (int q = 0; q < 8; ++q) {
        uint4 hv = hr[q];
        float f[8] = {bf_lo(hv.x), bf_hi(hv.x), bf_lo(hv.y), bf_hi(hv.y),
                      bf_lo(hv.z), bf_hi(hv.z), bf_lo(hv.w), bf_hi(hv.w)};
        #pragma unroll
        for (int i = 0; i < 8; ++i) {
            int k = q * 8 + i;
            a0 += f[i] * w_s[k * 3 + 0];
            a1 += f[i] * w_s[k * 3 + 1];
            a2 += f[i] * w_s[k * 3 + 2];
        }
    }
    uint2 o;
    o.x = bf16_pack2(a0, a1);
    o.y = bf16_pack2(a2, 0.f);
    *(uint2*)(z + (size_t)v * 2) = o;
}

// Final: out = verts + SCALE*(h3@Ws3 + nb3*inv_deg + b3); h3 bf16, nb fp32.
__global__ __launch_bounds__(256) void k_final(const unsigned int* __restrict__ h,
                                               const float* __restrict__ nb,
                                               const float* __restrict__ invdeg,
                                               const float* __restrict__ ws,
                                               const float* __restrict__ b,
                                               const float* __restrict__ verts,
                                               float* __restrict__ out, int nv) {
    __shared__ float w_s[64 * 3];
    if (threadIdx.x < 64 * 3) w_s[threadIdx.x] = ws[threadIdx.x];
    __syncthreads();
    int v = blockIdx.x * 256 + threadIdx.x;
    if (v >= nv) return;
    const uint4* hr = (const uint4*)(h + (size_t)v * 32);
    float a0 = b[0], a1 = b[1], a2 = b[2];
    #pragma unroll
    for (int q = 0; q < 8; ++q) {
        uint4 hv = hr[q];
        float f[8] = {bf_lo(hv.x), bf_hi(hv.x), bf_lo(hv.y), bf_hi(hv.y),
                      bf_lo(hv.z), bf_hi(hv.z), bf_lo(hv.w), bf_hi(hv.w)};
        #pragma unroll
        for (int i = 0; i < 8; ++i) {
            int k = q * 8 + i;
            a0 += f[i] * w_s[k * 3 + 0];
            a1 += f[i] * w_s[k * 3 + 1];
            a2 += f[i] * w_s[k * 3 + 2];
        }
    }
    float id = invdeg[v];
    float4 nq = *((const float4*)(nb + (size_t)v * 4));
    a0 += nq.x * id; a1 += nq.y * id; a2 += nq.z * id;
    out[(size_t)v * 3 + 0] = verts[(size_t)v * 3 + 0] + SCALE * a0;
    out[(size_t)v * 3 + 1] = verts[(size_t)v * 3 + 1] + SCALE * a1;
    out[(size_t)v * 3 + 2] = verts[(size_t)v * 3 + 2] + SCALE * a2;
}

// ---------------------------------------------------------------------------
extern "C" void kernel_launch(void* const* d_in, const int* in_sizes, int n_in,
                              void* d_out, int out_size, void* d_ws, size_t ws_size,
                              hipStream_t stream) {
    const float* img   = (const float*)d_in[0];
    const float* verts = (const float*)d_in[1];
    const int*   esrc  = (const int*)d_in[2];
    const int*   edst  = (const int*)d_in[3];
    const float* ws0 = (const float*)d_in[4];
    const float* wn0 = (const float*)d_in[5];
    const float* b0  = (const float*)d_in[6];
    const float* ws1 = (const float*)d_in[7];
    const float* wn1 = (const float*)d_in[8];
    const float* b1  = (const float*)d_in[9];
    const float* ws2 = (const float*)d_in[10];
    const float* wn2 = (const float*)d_in[11];
    const float* b2  = (const float*)d_in[12];
    const float* ws3 = (const float*)d_in[13];
    const float* wn3 = (const float*)d_in[14];
    const float* b3  = (const float*)d_in[15];

    const int nv = in_sizes[1] / 3;
    const int ne = in_sizes[2];

    char* base = (char*)d_ws;
    size_t off = 0;
    auto alloc = [&](size_t bytes) -> void* {
        off = (off + 255) & ~(size_t)255;
        void* p = base + off;
        off += bytes;
        return p;
    };
    int*   deg      = (int*)alloc((size_t)nv * 4);
    float* invdeg   = (float*)alloc((size_t)nv * 4);
    int*   rowStart = (int*)alloc((size_t)(nv + 1) * 4);
    int*   cursor   = (int*)alloc((size_t)nv * 4);
    int*   partials = (int*)alloc(256 * 4);
    int*   bucketCursor = (int*)alloc(256 * 4);
    int*   csrSrc   = (int*)alloc((size_t)ne * 4);
    unsigned int* A   = (unsigned int*)alloc((size_t)nv * 32 * 4);  // feats(16u) then h2(32u)
    unsigned int* B   = (unsigned int*)alloc((size_t)nv * 32 * 4);  // h1(16u) then h3(32u)
    unsigned int* NBu = (unsigned int*)alloc((size_t)nv * 32 * 4);  // bf16 neighbor sums
    float* NBz = (float*)alloc((size_t)nv * 4 * 4);                 // fp32 layer-3 nb
    unsigned int* Z   = (unsigned int*)alloc((size_t)nv * 2 * 4);   // bf16 premultiplied
    unsigned int* timg = (unsigned int*)alloc((size_t)VOL * 16 * 2);
    uint2* pairs = (uint2*)NBu;  // alias: ne*8 == nv*32*4 bytes exactly

    auto blocks = [](long long n) { return (int)((n + 255) / 256); };
    const int np = (nv + SCAN_TILE - 1) / SCAN_TILE;
    const int nbuckets = (nv + 511) >> 9;

    // Image transpose (independent of CSR build)
    k_transpose<<<(GRIDSZ * GRIDSZ * 32 * 4) / 256, 256, 0, stream>>>(img, timg);

    // CSR build: degree -> scan -> bucketed counting sort
    hipMemsetAsync(deg, 0, (size_t)nv * 4, stream);
    k_deg<<<blocks(ne), 256, 0, stream>>>(edst, deg, ne);
    k_scan1<<<np, 256, 0, stream>>>(deg, rowStart, partials, nv);
    k_scan2<<<1, 256, 0, stream>>>(partials, np);
    k_vinit<<<blocks(nv + 1), 256, 0, stream>>>(deg, rowStart, partials, invdeg, cursor, bucketCursor, nv, ne);
    k_bucket<<<(ne + EPB - 1) / EPB, 256, 0, stream>>>(esrc, edst, bucketCursor, pairs, ne);
    k_binsort<<<nbuckets, 256, 0, stream>>>(pairs, rowStart, cursor, csrSrc, nv);

    // Features (channel-last bf16 volume) -> bf16 feats
    k_sample<<<blocks((long long)nv * 2), 256, 0, stream>>>(timg, verts, A, nv);

    // Layer 0: 19 -> 32 (feats stride 16u)
    k_gather16<16><<<blocks((long long)nv * 4), 256, 0, stream>>>(A, rowStart, csrSrc, NBu, nv);
    k_layer16<19, 32, 16, true, true><<<(nv + 255) / 256, 256, 0, stream>>>(
        A, NBu, invdeg, ws0, wn0, b0, B, nv);

    // Layer 1: 32 -> 64 (h1 stride 16u)
    k_gather16<16><<<blocks((long long)nv * 4), 256, 0, stream>>>(B, rowStart, csrSrc, NBu, nv);
    k_layer16<32, 64, 16, true, false><<<(nv + 127) / 128, 256, 0, stream>>>(
        B, NBu, invdeg, ws1, wn1, b1, A, nv);

    // Layer 2: 64 -> 64 (h2 stride 32u)
    k_gather16<32><<<blocks((long long)nv * 8), 256, 0, stream>>>(A, rowStart, csrSrc, NBu, nv);
    k_layer16<64, 64, 32, true, false><<<(nv + 127) / 128, 256, 0, stream>>>(
        A, NBu, invdeg, ws2, wn2, b2, B, nv);

    // Layer 3: pre-multiply by Wn3 (64->3), gather bf16 z, fuse final update
    k_premul<<<blocks(nv), 256, 0, stream>>>(B, wn3, Z, nv);
    k_gatherz<<<blocks(nv), 256, 0, stream>>>(Z, rowStart, csrSrc, NBz, nv);
    k_final<<<blocks(nv), 256, 0, stream>>>(
        B, NBz, invdeg, ws3, b3, verts, (float*)d_out, nv);
}

// Round 8
// 523.967 us; speedup vs baseline: 2.2019x; 1.0773x over previous
//
#include <hip/hip_runtime.h>

// Problem constants (from reference)
#define C_IMG 16
#define GRIDSZ 128
#define VOL (GRIDSZ * GRIDSZ * GRIDSZ)
#define SLOPE 0.3f
#define SCALE 0.1f
#define EPB 4096         // edges per k_bucket block
#define HEPB 16384       // edges per k_hist block
#define BIN_CAP 16384    // max edges per 512-vertex bucket (mean 8192, sd ~90)

// bf16 helpers (manual, RNE pack / shift unpack)
__device__ __forceinline__ unsigned int bf16_pack2(float a, float b) {
    unsigned int ua = __float_as_uint(a);
    ua = (ua + 0x7FFFu + ((ua >> 16) & 1u)) >> 16;
    unsigned int ub = __float_as_uint(b);
    ub = (ub + 0x7FFFu + ((ub >> 16) & 1u)) >> 16;
    return ua | (ub << 16);
}
__device__ __forceinline__ float bf_lo(unsigned int u) { return __uint_as_float(u << 16); }
__device__ __forceinline__ float bf_hi(unsigned int u) { return __uint_as_float(u & 0xFFFF0000u); }

// ---------------------------------------------------------------------------
// Per-block LDS histogram of dst buckets (dst>>9), flushed with one global
// atomic per (block, bucket). Replaces per-edge global atomics of k_deg.
__global__ __launch_bounds__(256) void k_hist(const int* __restrict__ edst,
                                              int* __restrict__ bucketCount, int ne) {
    __shared__ int h[256];
    const int tid = threadIdx.x;
    h[tid] = 0;
    __syncthreads();
    const int base = blockIdx.x * HEPB;
    const int n = min(HEPB, ne - base);
    for (int i = tid; i < n; i += 256)
        atomicAdd(&h[((unsigned)edst[base + i]) >> 9], 1);
    __syncthreads();
    if (h[tid]) atomicAdd(&bucketCount[tid], h[tid]);
}

// Exclusive scan of <=256 bucket counts -> bucketBase (+ cursors); also sets
// bucketBase[np] = ne and rowStart[nv] = ne.
__global__ __launch_bounds__(256) void k_scan256(const int* __restrict__ bucketCount,
                                                 int* __restrict__ bucketBase,
                                                 int* __restrict__ bucketCursor,
                                                 int* __restrict__ rowStart,
                                                 int np, int nv, int ne) {
    __shared__ int buf[256];
    const int tid = threadIdx.x;
    const int v = (tid < np) ? bucketCount[tid] : 0;
    buf[tid] = v;
    __syncthreads();
    #pragma unroll
    for (int off = 1; off < 256; off <<= 1) {
        int t = (tid >= off) ? buf[tid - off] : 0;
        __syncthreads();
        buf[tid] += t;
        __syncthreads();
    }
    const int excl = buf[tid] - v;
    bucketBase[tid] = excl;
    bucketCursor[tid] = excl;
    if (tid == 0) {
        bucketBase[np] = ne;
        rowStart[nv] = ne;
    }
}

// Bucketing pass: group (dst,src) pairs by dst>>9 into per-bucket global
// regions with dense (coalesced-run) writes. LDS-staged local grouping.
__global__ __launch_bounds__(256) void k_bucket(const int* __restrict__ esrc,
                                                const int* __restrict__ edst,
                                                int* __restrict__ bucketCursor,
                                                uint2* __restrict__ pairs, int ne) {
    __shared__ unsigned int hist[256];
    __shared__ unsigned int pref[256];
    __shared__ unsigned int curs[256];
    __shared__ unsigned int gbase[256];
    __shared__ uint2 stage[EPB];
    const int tid = threadIdx.x;
    const int base = blockIdx.x * EPB;
    const int n = min(EPB, ne - base);
    hist[tid] = 0;
    __syncthreads();
    for (int i = tid; i < n; i += 256)
        atomicAdd(&hist[((unsigned)edst[base + i]) >> 9], 1u);
    __syncthreads();
    const unsigned int h = hist[tid];
    pref[tid] = h;
    __syncthreads();
    #pragma unroll
    for (int off = 1; off < 256; off <<= 1) {
        unsigned int t = (tid >= off) ? pref[tid - off] : 0;
        __syncthreads();
        pref[tid] += t;
        __syncthreads();
    }
    const unsigned int excl = pref[tid] - h;
    gbase[tid] = h ? (unsigned int)atomicAdd(&bucketCursor[tid], (int)h) : 0u;
    __syncthreads();
    pref[tid] = excl;
    curs[tid] = excl;
    __syncthreads();
    for (int i = tid; i < n; i += 256) {
        int d = edst[base + i];
        int s = esrc[base + i];
        unsigned int p = atomicAdd(&curs[((unsigned)d) >> 9], 1u);
        stage[p] = make_uint2((unsigned)d, (unsigned)s);
    }
    __syncthreads();
    for (int i = tid; i < n; i += 256) {
        uint2 pr = stage[i];
        unsigned int b = pr.x >> 9;
        pairs[gbase[b] + (unsigned)i - pref[b]] = pr;
    }
}

// Within-bucket: compute per-vertex degree + rowStart + invdeg in LDS, then
// scatter srcs via LDS cursors, flush coalesced. One block per 512-vtx bucket.
__global__ __launch_bounds__(256) void k_binsort(const uint2* __restrict__ pairs,
                                                 const int* __restrict__ bucketBase,
                                                 int* __restrict__ rowStart,
                                                 float* __restrict__ invdeg,
                                                 int* __restrict__ csrSrc, int nv) {
    __shared__ int deg_s[512];
    __shared__ int rs_s[512];
    __shared__ int cur_s[512];
    __shared__ int scan_s[256];
    __shared__ int outbuf[BIN_CAP];
    const int tid = threadIdx.x;
    const int b = blockIdx.x;
    const int vbase = b << 9;
    if (vbase >= nv) return;
    const int nvb = min(512, nv - vbase);
    const int gs = bucketBase[b];
    const int ge = bucketBase[b + 1];
    const int count = ge - gs;
    deg_s[tid] = 0;
    deg_s[tid + 256] = 0;
    __syncthreads();
    // pass 1: degrees
    for (int i = tid; i < count; i += 256) {
        uint2 p = pairs[gs + i];
        atomicAdd(&deg_s[p.x - (unsigned)vbase], 1);
    }
    __syncthreads();
    // scan 512 degrees (2 per thread)
    const int d0 = deg_s[2 * tid];
    const int d1 = deg_s[2 * tid + 1];
    const int ps = d0 + d1;
    scan_s[tid] = ps;
    __syncthreads();
    #pragma unroll
    for (int off = 1; off < 256; off <<= 1) {
        int t = (tid >= off) ? scan_s[tid - off] : 0;
        __syncthreads();
        scan_s[tid] += t;
        __syncthreads();
    }
    const int epair = scan_s[tid] - ps;
    rs_s[2 * tid] = epair;
    rs_s[2 * tid + 1] = epair + d0;
    cur_s[2 * tid] = epair;
    cur_s[2 * tid + 1] = epair + d0;
    #pragma unroll
    for (int u = 0; u < 2; ++u) {
        int idx = 2 * tid + u;
        if (idx < nvb) {
            rowStart[vbase + idx] = gs + rs_s[idx];
            int d = deg_s[idx];
            invdeg[vbase + idx] = 1.0f / (float)(d > 1 ? d : 1);
        }
    }
    __syncthreads();
    // pass 2: scatter
    if (count <= BIN_CAP) {
        for (int i = tid; i < count; i += 256) {
            uint2 p = pairs[gs + i];
            int pos = atomicAdd(&cur_s[p.x - (unsigned)vbase], 1);
            outbuf[pos] = (int)p.y;
        }
        __syncthreads();
        for (int i = tid; i < count; i += 256) csrSrc[gs + i] = outbuf[i];
    } else {
        // statistically unreachable; uncoalesced but correct
        for (int i = tid; i < count; i += 256) {
            uint2 p = pairs[gs + i];
            int pos = atomicAdd(&cur_s[p.x - (unsigned)vbase], 1);
            csrSrc[gs + pos] = (int)p.y;
        }
    }
}

// ---------------------------------------------------------------------------
// Image transpose: img[16][128][128][128] fp32 -> timg[x][y][z][16] bf16.
// 4 channels per thread (4 independent float4 loads before one vmcnt wait).
__global__ __launch_bounds__(256) void k_transpose(const float* __restrict__ img,
                                                   unsigned int* __restrict__ timg) {
    const int t = blockIdx.x * 256 + threadIdx.x;
    const int q  = t & 3;
    const int z4 = (t >> 2) & 31;
    const int xy = t >> 7;
    const int z0 = z4 * 4;
    const int c0 = q * 4;
    const size_t base = (size_t)xy * GRIDSZ + z0;
    float4 v0 = *(const float4*)(img + (size_t)(c0 + 0) * VOL + base);
    float4 v1 = *(const float4*)(img + (size_t)(c0 + 1) * VOL + base);
    float4 v2 = *(const float4*)(img + (size_t)(c0 + 2) * VOL + base);
    float4 v3 = *(const float4*)(img + (size_t)(c0 + 3) * VOL + base);
    #pragma unroll
    for (int j = 0; j < 4; ++j) {
        float f0 = (j == 0) ? v0.x : (j == 1) ? v0.y : (j == 2) ? v0.z : v0.w;
        float f1 = (j == 0) ? v1.x : (j == 1) ? v1.y : (j == 2) ? v1.z : v1.w;
        float f2 = (j == 0) ? v2.x : (j == 1) ? v2.y : (j == 2) ? v2.z : v2.w;
        float f3 = (j == 0) ? v3.x : (j == 1) ? v3.y : (j == 2) ? v3.z : v3.w;
        uint2 o;
        o.x = bf16_pack2(f0, f1);
        o.y = bf16_pack2(f2, f3);
        *(uint2*)(timg + (size_t)(xy * GRIDSZ + z0 + j) * 8 + q * 2) = o;
    }
}

// ---------------------------------------------------------------------------
// Trilinear sample -> bf16 feats rows, stride 16 uints (32 bf16 cols):
// cols 0..15 = channels, 16..18 = verts/128, 19..31 = 0.
__global__ __launch_bounds__(256) void k_sample(const unsigned int* __restrict__ timg,
                                                const float* __restrict__ verts,
                                                unsigned int* __restrict__ feats, int nv) {
    int t = blockIdx.x * 256 + threadIdx.x;
    int v = t >> 1;
    int q = t & 1;          // channel group: q*8 .. q*8+7
    if (v >= nv) return;
    float px = verts[v * 3 + 0];
    float py = verts[v * 3 + 1];
    float pz = verts[v * 3 + 2];
    float cx = fminf(fmaxf(px, 0.0f), 127.0f);
    float cy = fminf(fmaxf(py, 0.0f), 127.0f);
    float cz = fminf(fmaxf(pz, 0.0f), 127.0f);
    float fx = floorf(cx), fy = floorf(cy), fz = floorf(cz);
    int x0 = (int)fx, y0 = (int)fy, z0 = (int)fz;
    int x1 = min(x0 + 1, 127), y1 = min(y0 + 1, 127), z1 = min(z0 + 1, 127);
    float wx = cx - fx, wy = cy - fy, wz = cz - fz;
    const int qo = q * 4;
    #define LD(X, Y, Z) (*(const uint4*)(timg + ((size_t)((((X) << 7) + (Y)) << 7) + (size_t)(Z)) * 8 + qo))
    uint4 f000 = LD(x0, y0, z0), f001 = LD(x0, y0, z1);
    uint4 f010 = LD(x0, y1, z0), f011 = LD(x0, y1, z1);
    uint4 f100 = LD(x1, y0, z0), f101 = LD(x1, y0, z1);
    uint4 f110 = LD(x1, y1, z0), f111 = LD(x1, y1, z1);
    #undef LD
    float r[8];
    const unsigned int* a000 = (const unsigned int*)&f000;
    const unsigned int* a001 = (const unsigned int*)&f001;
    const unsigned int* a010 = (const unsigned int*)&f010;
    const unsigned int* a011 = (const unsigned int*)&f011;
    const unsigned int* a100 = (const unsigned int*)&f100;
    const unsigned int* a101 = (const unsigned int*)&f101;
    const unsigned int* a110 = (const unsigned int*)&f110;
    const unsigned int* a111 = (const unsigned int*)&f111;
    #pragma unroll
    for (int u = 0; u < 4; ++u) {
        float c00l = bf_lo(a000[u]) * (1.f - wz) + bf_lo(a001[u]) * wz;
        float c01l = bf_lo(a010[u]) * (1.f - wz) + bf_lo(a011[u]) * wz;
        float c10l = bf_lo(a100[u]) * (1.f - wz) + bf_lo(a101[u]) * wz;
        float c11l = bf_lo(a110[u]) * (1.f - wz) + bf_lo(a111[u]) * wz;
        r[2 * u] = (c00l * (1.f - wy) + c01l * wy) * (1.f - wx) +
                   (c10l * (1.f - wy) + c11l * wy) * wx;
        float c00h = bf_hi(a000[u]) * (1.f - wz) + bf_hi(a001[u]) * wz;
        float c01h = bf_hi(a010[u]) * (1.f - wz) + bf_hi(a011[u]) * wz;
        float c10h = bf_hi(a100[u]) * (1.f - wz) + bf_hi(a101[u]) * wz;
        float c11h = bf_hi(a110[u]) * (1.f - wz) + bf_hi(a111[u]) * wz;
        r[2 * u + 1] = (c00h * (1.f - wy) + c01h * wy) * (1.f - wx) +
                       (c10h * (1.f - wy) + c11h * wy) * wx;
    }
    unsigned int* row = feats + (size_t)v * 16;
    uint4 o;
    o.x = bf16_pack2(r[0], r[1]); o.y = bf16_pack2(r[2], r[3]);
    o.z = bf16_pack2(r[4], r[5]); o.w = bf16_pack2(r[6], r[7]);
    *(uint4*)(row + q * 4) = o;
    if (q == 0) {
        uint4 o2;
        o2.x = bf16_pack2(px * (1.0f / 128.0f), py * (1.0f / 128.0f));
        o2.y = bf16_pack2(pz * (1.0f / 128.0f), 0.0f);
        o2.z = 0u; o2.w = 0u;
        *(uint4*)(row + 8) = o2;
        *(uint4*)(row + 12) = make_uint4(0u, 0u, 0u, 0u);
    }
}

// ---------------------------------------------------------------------------
// CSR gather-sum over bf16 rows (stride SU uints). NCH=SU/4 threads per
// vertex, each owns a uint4 (8 ch) chunk; fp32 accumulate, bf16 output.
template <int SU>
__global__ __launch_bounds__(256) void k_gather16(const unsigned int* __restrict__ x,
                                                  const int* __restrict__ rowStart,
                                                  const int* __restrict__ csrSrc,
                                                  unsigned int* __restrict__ nb, int nv) {
    constexpr int NCH = SU / 4;
    int t = blockIdx.x * 256 + threadIdx.x;
    int v = t / NCH;
    if (v >= nv) return;
    int ch = t - v * NCH;
    int beg = rowStart[v];
    int end = rowStart[v + 1];
    float a0 = 0.f, a1 = 0.f, a2 = 0.f, a3 = 0.f, a4 = 0.f, a5 = 0.f, a6 = 0.f, a7 = 0.f;
    for (int j = beg; j < end; ++j) {
        int s = csrSrc[j];
        uint4 q = ((const uint4*)(x + (size_t)s * SU))[ch];
        a0 += bf_lo(q.x); a1 += bf_hi(q.x);
        a2 += bf_lo(q.y); a3 += bf_hi(q.y);
        a4 += bf_lo(q.z); a5 += bf_hi(q.z);
        a6 += bf_lo(q.w); a7 += bf_hi(q.w);
    }
    uint4 o;
    o.x = bf16_pack2(a0, a1); o.y = bf16_pack2(a2, a3);
    o.z = bf16_pack2(a4, a5); o.w = bf16_pack2(a6, a7);
    ((uint4*)(nb + (size_t)v * SU))[ch] = o;
}

// ---------------------------------------------------------------------------
// Edge-conv dense part over bf16 x/nb (stride SXU uints), bf16 out (COUT/2
// uints). Weights fp32 in LDS. REMAP0: srcrow = k<16 ? k+3 : k-16.
template <int CIN, int COUT, int SXU, bool RELU, bool REMAP0>
__global__ __launch_bounds__(256) void k_layer16(const unsigned int* __restrict__ x,
                                                 const unsigned int* __restrict__ nb,
                                                 const float* __restrict__ invdeg,
                                                 const float* __restrict__ Ws,
                                                 const float* __restrict__ Wn,
                                                 const float* __restrict__ b,
                                                 unsigned int* __restrict__ out, int nv) {
    constexpr int GR = COUT / 8;
    constexpr int VPT = 4;
    constexpr int TPB = 256;
    constexpr int VPB = (TPB / GR) * VPT;
    constexpr int KP = (CIN + 3) & ~3;
    constexpr int SOU = COUT / 2;
    __shared__ float ws_s[KP * COUT];
    __shared__ float wn_s[KP * COUT];
    for (int i = threadIdx.x; i < KP * COUT; i += TPB) {
        int k = i / COUT, c = i - k * COUT;
        float vs = 0.f, vn = 0.f;
        if (k < CIN) {
            int sr = REMAP0 ? ((k < 16) ? (k + 3) : (k - 16)) : k;
            vs = Ws[sr * COUT + c];
            vn = Wn[sr * COUT + c];
        }
        ws_s[i] = vs;
        wn_s[i] = vn;
    }
    __syncthreads();

    const int g = threadIdx.x % GR;
    const int co = g * 8;
    const int vt = threadIdx.x / GR;
    const int v0 = blockIdx.x * VPB + vt * VPT;

    float acc_s[VPT][8], acc_n[VPT][8];
    #pragma unroll
    for (int u = 0; u < VPT; ++u)
        #pragma unroll
        for (int i = 0; i < 8; ++i) { acc_s[u][i] = 0.f; acc_n[u][i] = 0.f; }

    for (int k = 0; k < KP; k += 4) {
        uint2 xq[VPT], nq[VPT];
        #pragma unroll
        for (int u = 0; u < VPT; ++u) {
            int v = v0 + u;
            if (v < nv) {
                xq[u] = *(const uint2*)(x + (size_t)v * SXU + (k >> 1));
                nq[u] = *(const uint2*)(nb + (size_t)v * SXU + (k >> 1));
            } else {
                xq[u] = make_uint2(0u, 0u);
                nq[u] = make_uint2(0u, 0u);
            }
        }
        #pragma unroll
        for (int j = 0; j < 4; ++j) {
            const float4 wsa = *(const float4*)(ws_s + (k + j) * COUT + co);
            const float4 wsb = *(const float4*)(ws_s + (k + j) * COUT + co + 4);
            const float4 wna = *(const float4*)(wn_s + (k + j) * COUT + co);
            const float4 wnb = *(const float4*)(wn_s + (k + j) * COUT + co + 4);
            #pragma unroll
            for (int u = 0; u < VPT; ++u) {
                float xv = (j == 0) ? bf_lo(xq[u].x) : (j == 1) ? bf_hi(xq[u].x)
                         : (j == 2) ? bf_lo(xq[u].y) : bf_hi(xq[u].y);
                float nw = (j == 0) ? bf_lo(nq[u].x) : (j == 1) ? bf_hi(nq[u].x)
                         : (j == 2) ? bf_lo(nq[u].y) : bf_hi(nq[u].y);
                acc_s[u][0] += xv * wsa.x; acc_s[u][1] += xv * wsa.y;
                acc_s[u][2] += xv * wsa.z; acc_s[u][3] += xv * wsa.w;
                acc_s[u][4] += xv * wsb.x; acc_s[u][5] += xv * wsb.y;
                acc_s[u][6] += xv * wsb.z; acc_s[u][7] += xv * wsb.w;
                acc_n[u][0] += nw * wna.x; acc_n[u][1] += nw * wna.y;
                acc_n[u][2] += nw * wna.z; acc_n[u][3] += nw * wna.w;
                acc_n[u][4] += nw * wnb.x; acc_n[u][5] += nw * wnb.y;
                acc_n[u][6] += nw * wnb.z; acc_n[u][7] += nw * wnb.w;
            }
        }
    }

    #pragma unroll
    for (int u = 0; u < VPT; ++u) {
        int v = v0 + u;
        if (v >= nv) continue;
        float id = invdeg[v];
        float r[8];
        #pragma unroll
        for (int i = 0; i < 8; ++i) {
            float t = acc_s[u][i] + acc_n[u][i] * id + b[co + i];
            r[i] = (!RELU || t >= 0.f) ? t : SLOPE * t;
        }
        uint4 o;
        o.x = bf16_pack2(r[0], r[1]); o.y = bf16_pack2(r[2], r[3]);
        o.z = bf16_pack2(r[4], r[5]); o.w = bf16_pack2(r[6], r[7]);
        *(uint4*)(out + (size_t)v * SOU + (co >> 1)) = o;
    }
}

// Pre-multiply for layer 3: z[v] = h3[v] @ Wn3 (3 cols), bf16 in/out.
__global__ __launch_bounds__(256) void k_premul(const unsigned int* __restrict__ h,
                                                const float* __restrict__ wn,
                                                unsigned int* __restrict__ z, int nv) {
    __shared__ float w_s[64 * 3];
    if (threadIdx.x < 64 * 3) w_s[threadIdx.x] = wn[threadIdx.x];
    __syncthreads();
    int v = blockIdx.x * 256 + threadIdx.x;
    if (v >= nv) return;
    const uint4* hr = (const uint4*)(h + (size_t)v * 32);
    float a0 = 0.f, a1 = 0.f, a2 = 0.f;
    #pragma unroll
    for (int q = 0; q < 8; ++q) {
        uint4 hv = hr[q];
        float f[8] = {bf_lo(hv.x), bf_hi(hv.x), bf_lo(hv.y), bf_hi(hv.y),
                      bf_lo(hv.z), bf_hi(hv.z), bf_lo(hv.w), bf_hi(hv.w)};
        #pragma unroll
        for (int i = 0; i < 8; ++i) {
            int k = q * 8 + i;
            a0 += f[i] * w_s[k * 3 + 0];
            a1 += f[i] * w_s[k * 3 + 1];
            a2 += f[i] * w_s[k * 3 + 2];
        }
    }
    uint2 o;
    o.x = bf16_pack2(a0, a1);
    o.y = bf16_pack2(a2, 0.f);
    *(uint2*)(z + (size_t)v * 2) = o;
}

// Final (fused z-gather): out = verts + SCALE*(h3@Ws3 + gather(z)*inv_deg + b3)
__global__ __launch_bounds__(256) void k_final(const unsigned int* __restrict__ h,
                                               const unsigned int* __restrict__ z,
                                               const int* __restrict__ rowStart,
                                               const int* __restrict__ csrSrc,
                                               const float* __restrict__ invdeg,
                                               const float* __restrict__ ws,
                                               const float* __restrict__ b,
                                               const float* __restrict__ verts,
                                               float* __restrict__ out, int nv) {
    __shared__ float w_s[64 * 3];
    if (threadIdx.x < 64 * 3) w_s[threadIdx.x] = ws[threadIdx.x];
    __syncthreads();
    int v = blockIdx.x * 256 + threadIdx.x;
    if (v >= nv) return;
    // neighbor gather of premultiplied z (800 KB, L2-resident)
    float n0 = 0.f, n1 = 0.f, n2 = 0.f;
    {
        int beg = rowStart[v];
        int end = rowStart[v + 1];
        for (int j = beg; j < end; ++j) {
            int s = csrSrc[j];
            uint2 q = *(const uint2*)(z + (size_t)s * 2);
            n0 += bf_lo(q.x); n1 += bf_hi(q.x); n2 += bf_lo(q.y);
        }
    }
    const uint4* hr = (const uint4*)(h + (size_t)v * 32);
    float a0 = b[0], a1 = b[1], a2 = b[2];
    #pragma unroll
    for (int q = 0; q < 8; ++q) {
        uint4 hv = hr[q];
        float f[8] = {bf_lo(hv.x), bf_hi(hv.x), bf_lo(hv.y), bf_hi(hv.y),
                      bf_lo(hv.z), bf_hi(hv.z), bf_lo(hv.w), bf_hi(hv.w)};
        #pragma unroll
        for (int i = 0; i < 8; ++i) {
            int k = q * 8 + i;
            a0 += f[i] * w_s[k * 3 + 0];
            a1 += f[i] * w_s[k * 3 + 1];
            a2 += f[i] * w_s[k * 3 + 2];
        }
    }
    float id = invdeg[v];
    a0 += n0 * id; a1 += n1 * id; a2 += n2 * id;
    out[(size_t)v * 3 + 0] = verts[(size_t)v * 3 + 0] + SCALE * a0;
    out[(size_t)v * 3 + 1] = verts[(size_t)v * 3 + 1] + SCALE * a1;
    out[(size_t)v * 3 + 2] = verts[(size_t)v * 3 + 2] + SCALE * a2;
}

// ---------------------------------------------------------------------------
extern "C" void kernel_launch(void* const* d_in, const int* in_sizes, int n_in,
                              void* d_out, int out_size, void* d_ws, size_t ws_size,
                              hipStream_t stream) {
    const float* img   = (const float*)d_in[0];
    const float* verts = (const float*)d_in[1];
    const int*   esrc  = (const int*)d_in[2];
    const int*   edst  = (const int*)d_in[3];
    const float* ws0 = (const float*)d_in[4];
    const float* wn0 = (const float*)d_in[5];
    const float* b0  = (const float*)d_in[6];
    const float* ws1 = (const float*)d_in[7];
    const float* wn1 = (const float*)d_in[8];
    const float* b1  = (const float*)d_in[9];
    const float* ws2 = (const float*)d_in[10];
    const float* wn2 = (const float*)d_in[11];
    const float* b2  = (const float*)d_in[12];
    const float* ws3 = (const float*)d_in[13];
    const float* wn3 = (const float*)d_in[14];
    const float* b3  = (const float*)d_in[15];

    const int nv = in_sizes[1] / 3;
    const int ne = in_sizes[2];

    char* base = (char*)d_ws;
    size_t off = 0;
    auto alloc = [&](size_t bytes) -> void* {
        off = (off + 255) & ~(size_t)255;
        void* p = base + off;
        off += bytes;
        return p;
    };
    float* invdeg   = (float*)alloc((size_t)nv * 4);
    int*   rowStart = (int*)alloc((size_t)(nv + 1) * 4);
    int*   bucketCount  = (int*)alloc(256 * 4);
    int*   bucketBase   = (int*)alloc(257 * 4);
    int*   bucketCursor = (int*)alloc(256 * 4);
    int*   csrSrc   = (int*)alloc((size_t)ne * 4);
    unsigned int* A   = (unsigned int*)alloc((size_t)nv * 32 * 4);  // feats(16u) then h2(32u)
    unsigned int* B   = (unsigned int*)alloc((size_t)nv * 32 * 4);  // h1(16u) then h3(32u)
    unsigned int* NBu = (unsigned int*)alloc((size_t)nv * 32 * 4);  // bf16 neighbor sums
    unsigned int* Z   = (unsigned int*)alloc((size_t)nv * 2 * 4);   // bf16 premultiplied
    unsigned int* timg = (unsigned int*)alloc((size_t)VOL * 16 * 2);
    uint2* pairs = (uint2*)NBu;  // alias: ne*8 == nv*32*4 bytes exactly

    auto blocks = [](long long n) { return (int)((n + 255) / 256); };
    const int nbuckets = (nv + 511) >> 9;

    // Image transpose (independent of CSR build)
    k_transpose<<<(GRIDSZ * GRIDSZ * 32 * 4) / 256, 256, 0, stream>>>(img, timg);

    // CSR build: bucket histogram -> scan -> bucketing -> per-bucket sort
    hipMemsetAsync(bucketCount, 0, 256 * 4, stream);
    k_hist<<<(ne + HEPB - 1) / HEPB, 256, 0, stream>>>(edst, bucketCount, ne);
    k_scan256<<<1, 256, 0, stream>>>(bucketCount, bucketBase, bucketCursor, rowStart, nbuckets, nv, ne);
    k_bucket<<<(ne + EPB - 1) / EPB, 256, 0, stream>>>(esrc, edst, bucketCursor, pairs, ne);
    k_binsort<<<nbuckets, 256, 0, stream>>>(pairs, bucketBase, rowStart, invdeg, csrSrc, nv);

    // Features (channel-last bf16 volume) -> bf16 feats
    k_sample<<<blocks((long long)nv * 2), 256, 0, stream>>>(timg, verts, A, nv);

    // Layer 0: 19 -> 32 (feats stride 16u)
    k_gather16<16><<<blocks((long long)nv * 4), 256, 0, stream>>>(A, rowStart, csrSrc, NBu, nv);
    k_layer16<19, 32, 16, true, true><<<(nv + 255) / 256, 256, 0, stream>>>(
        A, NBu, invdeg, ws0, wn0, b0, B, nv);

    // Layer 1: 32 -> 64 (h1 stride 16u)
    k_gather16<16><<<blocks((long long)nv * 4), 256, 0, stream>>>(B, rowStart, csrSrc, NBu, nv);
    k_layer16<32, 64, 16, true, false><<<(nv + 127) / 128, 256, 0, stream>>>(
        B, NBu, invdeg, ws1, wn1, b1, A, nv);

    // Layer 2: 64 -> 64 (h2 stride 32u)
    k_gather16<32><<<blocks((long long)nv * 8), 256, 0, stream>>>(A, rowStart, csrSrc, NBu, nv);
    k_layer16<64, 64, 32, true, false><<<(nv + 127) / 128, 256, 0, stream>>>(
        A, NBu, invdeg, ws2, wn2, b2, B, nv);

    // Layer 3: pre-multiply by Wn3 (64->3), fused gather+final update
    k_premul<<<blocks(nv), 256, 0, stream>>>(B, wn3, Z, nv);
    k_final<<<blocks(nv), 256, 0, stream>>>(
        B, Z, rowStart, csrSrc, invdeg, ws3, b3, verts, (float*)d_out, nv);
}